// Round 1
// baseline (292.418 us; speedup 1.0000x reference)
//
#include <hip/hip_runtime.h>
#include <math.h>

typedef float    floatx4 __attribute__((ext_vector_type(4)));
typedef _Float16 half8   __attribute__((ext_vector_type(8)));
typedef _Float16 half4v  __attribute__((ext_vector_type(4)));
typedef _Float16 half2v  __attribute__((ext_vector_type(2)));
typedef __fp16   fp16x2  __attribute__((ext_vector_type(2)));

constexpr int B    = 2;
constexpr int S    = 2048;
constexpr int NH   = 16;
constexpr int HD   = 64;
constexpr int DIM  = 1024;
constexpr int INNER = 1024;
constexpr int QKVN = 3072;
constexpr int NTOK = 4096;
constexpr float EPS = 1e-5f;
constexpr float MAX_SCALE = 10.0f;
constexpr float SCALE_LOG2E = 0.125f * 1.4426950408889634f;

#define MFMA16(a, b, c) __builtin_amdgcn_mfma_f32_16x16x16f16((a), (b), (c), 0, 0, 0)

__device__ __forceinline__ half2v pkrtz(float a, float b) {
  fp16x2 t = __builtin_amdgcn_cvt_pkrtz(a, b);
  return __builtin_bit_cast(half2v, t);
}
__device__ __forceinline__ half2v hmax2(half2v a, half2v b) {
  return __builtin_elementwise_max(a, b);
}

// Direct global->LDS DMA, 16 B per lane. LDS dest must be wave-uniform base;
// HW writes at base + lane*16 (linear).
__device__ __forceinline__ void gl_lds16(const _Float16* g, _Float16* l) {
  __builtin_amdgcn_global_load_lds(
      (__attribute__((address_space(1))) void*)g,
      (__attribute__((address_space(3))) void*)l, 16, 0, 0);
}

// ---------------------------------------------------------------------------
// Fused prep: blockIdx [0,2048) fp32->fp16 convert of hs;
// [2048,2816) transpose w_qkv; [2816,3072) transpose w_out.
// ---------------------------------------------------------------------------
__device__ __forceinline__ void transpose_tile(const float* __restrict__ w,
                                               _Float16* __restrict__ wT,
                                               int K, int N, int k0, int n0,
                                               _Float16* T, int tid) {
#pragma unroll
  for (int i = 0; i < 4; ++i) {
    int id = tid + 256 * i;
    int r = id >> 4, c = id & 15;
    float4 v = *(const float4*)&w[(size_t)(k0 + r) * N + n0 + c * 4];
    half4v s; s[0] = (_Float16)v.x; s[1] = (_Float16)v.y;
    s[2] = (_Float16)v.z; s[3] = (_Float16)v.w;
    *(half4v*)&T[r * 72 + c * 4] = s;
  }
  __syncthreads();
#pragma unroll
  for (int i = 0; i < 2; ++i) {
    int id = tid + 256 * i;
    int n = id >> 3, cs = id & 7;
    half8 o;
#pragma unroll
    for (int jj = 0; jj < 8; ++jj) o[jj] = T[(cs * 8 + jj) * 72 + n];
    *(half8*)&wT[(size_t)(n0 + n) * K + k0 + cs * 8] = o;
  }
}

__global__ __launch_bounds__(256)
void prep_all(const float* __restrict__ hs, const float* __restrict__ w_qkv,
              const float* __restrict__ w_out, _Float16* __restrict__ hsb,
              _Float16* __restrict__ wqkvT, _Float16* __restrict__ woutT) {
  __shared__ _Float16 T[64 * 72];
  const int bx = blockIdx.x, tid = threadIdx.x;
  if (bx < 2048) {
    int id = bx * 256 + tid;
    const float4 a = ((const float4*)hs)[id * 2];
    const float4 b = ((const float4*)hs)[id * 2 + 1];
    half8 o;
    o[0] = (_Float16)a.x; o[1] = (_Float16)a.y; o[2] = (_Float16)a.z; o[3] = (_Float16)a.w;
    o[4] = (_Float16)b.x; o[5] = (_Float16)b.y; o[6] = (_Float16)b.z; o[7] = (_Float16)b.w;
    ((half8*)hsb)[id] = o;
  } else if (bx < 2816) {
    int id = bx - 2048;
    transpose_tile(w_qkv, wqkvT, DIM, QKVN, (id / 48) * 64, (id % 48) * 64, T, tid);
  } else {
    int id = bx - 2816;
    transpose_tile(w_out, woutT, INNER, DIM, (id / 16) * 64, (id % 16) * 64, T, tid);
  }
}

// ---------------------------------------------------------------------------
// fp16 MFMA GEMM, m97 structure: global_load_lds width-16 staging, BK=64,
// linear LDS dest + XOR-pre-swizzled global source (T2, rule #21):
//   LDS[r][chunk c] = G[r][chunk c ^ (r&7)]   (chunks of 16 B)
// so fragment ds_read_b128 at chunk g reads LDS chunk g^(r&7): 2-way, free.
// ---------------------------------------------------------------------------
template<bool OUT_F16, typename OutT>
__global__ __launch_bounds__(256)
void gemm_bt(const _Float16* __restrict__ A, const _Float16* __restrict__ BT,
             const float* __restrict__ bias, OutT* __restrict__ C, int N, int K) {
  __shared__ _Float16 As[128 * 64];
  __shared__ _Float16 Bs[128 * 64];
  const int tid = threadIdx.x;
  const int wave = tid >> 6, lane = tid & 63, quad = lane >> 4, l16 = lane & 15;
  const int wm = wave >> 1, wn = wave & 1;
  const int m0 = blockIdx.y * 128, n0 = blockIdx.x * 128;

  // staging geometry: instr i of wave w covers rows i*32 + w*8 .. +8.
  // lane l -> row + (l>>3), dest 16B-chunk c = l&7; source chunk = c ^ (row&7).
  const int srow = lane >> 3;
  const int scolh = ((lane & 7) ^ srow) * 8;   // row&7 == srow (row bases are x8)
  const _Float16* Ag = A  + (size_t)(m0 + wave * 8 + srow) * K + scolh;
  const _Float16* Bg = BT + (size_t)(n0 + wave * 8 + srow) * K + scolh;

  floatx4 acc[4][4] = {};
  const int rx = l16 & 7;

  for (int k0 = 0; k0 < K; k0 += 64) {
#pragma unroll
    for (int i = 0; i < 4; ++i) {
      gl_lds16(Ag + (size_t)i * 32 * K + k0, As + (i * 4 + wave) * 512);
      gl_lds16(Bg + (size_t)i * 32 * K + k0, Bs + (i * 4 + wave) * 512);
    }
    __syncthreads();   // vmcnt(0) drain: staged tile visible to all waves
#pragma unroll
    for (int ks = 0; ks < 2; ++ks) {
      half8 a[4], b[4];
#pragma unroll
      for (int i = 0; i < 4; ++i)
        a[i] = *(const half8*)&As[(wm * 64 + i * 16 + l16) * 64 + (((ks * 4 + quad) ^ rx) * 8)];
#pragma unroll
      for (int j = 0; j < 4; ++j)
        b[j] = *(const half8*)&Bs[(wn * 64 + j * 16 + l16) * 64 + (((ks * 4 + quad) ^ rx) * 8)];
#pragma unroll
      for (int i = 0; i < 4; ++i)
#pragma unroll
        for (int j = 0; j < 4; ++j)
          acc[i][j] = __builtin_amdgcn_mfma_f32_16x16x32_f16(a[i], b[j], acc[i][j], 0, 0, 0);
    }
    __syncthreads();   // all reads done before next tile overwrites
  }

  const int rb = m0 + wm * 64 + quad * 4;
  const int cb = n0 + wn * 64 + l16;
#pragma unroll
  for (int j = 0; j < 4; ++j) {
    const float bj = bias[cb + j * 16];
#pragma unroll
    for (int i = 0; i < 4; ++i) {
#pragma unroll
      for (int r = 0; r < 4; ++r) {
        float v = acc[i][j][r] + bj;
        size_t idx = (size_t)(rb + i * 16 + r) * N + cb + j * 16;
        if constexpr (OUT_F16) C[idx] = (_Float16)v; else C[idx] = v;
      }
    }
  }
}

// ---------------------------------------------------------------------------
// Fused post: blockIdx [0,4096) = per-token RMSNorm+rotary+hist-scale;
// [4096,5120) = V transpose/swizzle tiles (fragment order for PV MFMAs).
// ---------------------------------------------------------------------------
__global__ __launch_bounds__(256)
void post_all(const _Float16* __restrict__ qkvh, const float* __restrict__ rot,
              const float* __restrict__ nqw, const float* __restrict__ nkw,
              const float* __restrict__ hks, const int* __restrict__ octx,
              _Float16* __restrict__ qo_, _Float16* __restrict__ ko_,
              _Float16* __restrict__ vt) {
  __shared__ __align__(16) char arena[64 * 72 * 2];
  const int tid = threadIdx.x;
  if (blockIdx.x < 4096) {
    float* red = (float*)arena;
    const int token = blockIdx.x;
    const int b = token >> 11, spos = token & (S - 1);
    const _Float16* qrow = qkvh + (size_t)token * QKVN;
    const _Float16* krow = qrow + INNER;
    const float* r = rot + (size_t)token * (2 * HD);

    const int e0 = tid * 4;
    half4v qs = *(const half4v*)(qrow + e0);
    half4v ks = *(const half4v*)(krow + e0);
    float q4[4], k4[4];
#pragma unroll
    for (int i = 0; i < 4; ++i) { q4[i] = (float)qs[i]; k4[i] = (float)ks[i]; }

    float sq = 0.f, sk = 0.f;
#pragma unroll
    for (int i = 0; i < 4; ++i) { sq += q4[i] * q4[i]; sk += k4[i] * k4[i]; }
#pragma unroll
    for (int msk = 1; msk < 64; msk <<= 1) {
      sq += __shfl_xor(sq, msk);
      sk += __shfl_xor(sk, msk);
    }
    const int wv = tid >> 6;
    if ((tid & 63) == 0) { red[wv] = sq; red[4 + wv] = sk; }
    __syncthreads();
    sq = red[0] + red[1] + red[2] + red[3];
    sk = red[4] + red[5] + red[6] + red[7];

    const float qinv = 1.0f / sqrtf(sq * (1.0f / INNER) + EPS);
    const float kinv = 1.0f / sqrtf(sk * (1.0f / INNER) + EPS);

#pragma unroll
    for (int i = 0; i < 4; ++i) {
      q4[i] = q4[i] * qinv * nqw[e0 + i];
      k4[i] = k4[i] * kinv * nkw[e0 + i];
    }

    const int h = e0 >> 6, d0 = e0 & (HD - 1);
    const float c0 = r[d0],     s0 = r[HD + d0 + 1];
    const float c1 = r[d0 + 2], s1 = r[HD + d0 + 3];

    float qo[4], ko[4];
    qo[0] = q4[0] * c0 - q4[1] * s0;
    qo[1] = q4[0] * s0 + q4[1] * c0;
    qo[2] = q4[2] * c1 - q4[3] * s1;
    qo[3] = q4[2] * s1 + q4[3] * c1;
    ko[0] = k4[0] * c0 - k4[1] * s0;
    ko[1] = k4[0] * s0 + k4[1] * c0;
    ko[2] = k4[2] * c1 - k4[3] * s1;
    ko[3] = k4[2] * s1 + k4[3] * c1;

    const int hist = S - octx[0];
    if (hist > 0 && spos < hist) {
      const float sig = 1.0f / (1.0f + expf(-hks[h]));
      const float sc = 1.0f + sig * (MAX_SCALE - 1.0f);
#pragma unroll
      for (int i = 0; i < 4; ++i) ko[i] *= sc;
    }

    half4v qo4, ko4;
#pragma unroll
    for (int i = 0; i < 4; ++i) {
      qo4[i] = (_Float16)(qo[i] * SCALE_LOG2E);
      ko4[i] = (_Float16)ko[i];
    }
    const size_t obase = ((size_t)(b * NH + h) * S + spos) * HD + d0;
    *(half4v*)(qo_ + obase) = qo4;
    *(half4v*)(ko_ + obase) = ko4;
  } else {
    _Float16* T = (_Float16*)arena;
    const int id = blockIdx.x - 4096;
    const int bh = id & 31, kt = id >> 5;
    const int b = bh >> 4, h = bh & 15;
    const int s0 = kt * 64;
#pragma unroll
    for (int i = 0; i < 2; ++i) {
      int id2 = tid + 256 * i;
      int s = id2 >> 3, c = id2 & 7;
      *(half8*)&T[s * 72 + c * 8] =
          *(const half8*)&qkvh[(size_t)(b * S + s0 + s) * QKVN + 2 * INNER + h * HD + c * 8];
    }
    __syncthreads();
    _Float16* orow = vt + ((size_t)bh * 32 + kt) * 64 * 64;
#pragma unroll
    for (int i = 0; i < 4; ++i) {
      int id2 = tid + 256 * i;
      int d = id2 >> 4, g = id2 & 15;
      int quad = g >> 2, jj = g & 3;
      half4v o;
#pragma unroll
      for (int k = 0; k < 4; ++k) o[k] = T[(jj * 16 + quad * 4 + k) * 72 + d];
      *(half4v*)&orow[d * 64 + g * 4] = o;
    }
  }
}

// ---------------------------------------------------------------------------
// MFMA flash attention: 512 thr = 8 waves, 128-row Q tile. K double-buffered
// in LDS; V read DIRECTLY from global (L2-resident fragment-ordered vT) —
// no V staging, no V LDS reads (m169: LDS-staging L2-fit data is overhead).
// Packed-f16 softmax with defer-max (THR=4 in log2 domain).
// ---------------------------------------------------------------------------
__global__ __launch_bounds__(512)
void attn_mfma(const _Float16* __restrict__ qb, const _Float16* __restrict__ kb,
               const _Float16* __restrict__ vt, _Float16* __restrict__ attnb) {
  __shared__ _Float16 Kb0[64 * 72];
  __shared__ _Float16 Kb1[64 * 72];
  const int bh = blockIdx.x;
  const int b = bh >> 4, h = bh & 15;
  const int q0 = blockIdx.y * 128;
  const int tid = threadIdx.x;
  const int wave = tid >> 6, lane = tid & 63, quad = lane >> 4, l16 = lane & 15;

  const _Float16* qbh = qb + (size_t)bh * S * HD;
  const _Float16* kbh = kb + (size_t)bh * S * HD;
  const _Float16* vbh = vt + (size_t)bh * S * HD;

  half8 aq[2];
#pragma unroll
  for (int ks = 0; ks < 2; ++ks)
    aq[ks] = *(const half8*)&qbh[(size_t)(q0 + wave * 16 + l16) * HD + ks * 32 + quad * 8];

  const int rr = tid >> 3, cc = (tid & 7) * 8;
  const _Float16* kptr = kbh + (size_t)rr * HD + cc;

  half8 kreg = *(const half8*)kptr;                 // tile 0
  *(half8*)&Kb0[rr * 72 + cc] = kreg;
  kptr += 64 * HD;
  kreg = *(const half8*)kptr;                       // tile 1
  __syncthreads();

  floatx4 o16[4] = {};
  float mrow = -INFINITY, lrow = 0.f;

  auto compute = [&](const _Float16* Kp, const _Float16* Vg) {
    // Issue V loads first: L2 latency hides under QK^T MFMAs + softmax VALU.
    half8 v01[4], v23[4];
#pragma unroll
    for (int jb = 0; jb < 4; ++jb) {
      v01[jb] = *(const half8*)&Vg[(jb * 16 + l16) * 64 + quad * 16];
      v23[jb] = *(const half8*)&Vg[(jb * 16 + l16) * 64 + quad * 16 + 8];
    }

    // S^T = K @ Q^T : sc[jj][r] = S[qrow=l16][kcol = jj*16+quad*4+r]
    floatx4 sc[4] = {};
#pragma unroll
    for (int jj = 0; jj < 4; ++jj) {
#pragma unroll
      for (int ks = 0; ks < 2; ++ks) {
        half8 ak = *(const half8*)&Kp[(jj * 16 + l16) * 72 + ks * 32 + quad * 8];
        sc[jj] = __builtin_amdgcn_mfma_f32_16x16x32_f16(ak, aq[ks], sc[jj], 0, 0, 0);
      }
    }

    // ---- packed f16 online softmax (log2 domain; scale pre-folded in q) ----
    half2v ph[8];
#pragma unroll
    for (int jj = 0; jj < 4; ++jj) {
      ph[jj * 2]     = pkrtz(sc[jj][0], sc[jj][1]);
      ph[jj * 2 + 1] = pkrtz(sc[jj][2], sc[jj][3]);
    }
    half2v m0 = hmax2(hmax2(ph[0], ph[1]), hmax2(ph[2], ph[3]));
    half2v m1 = hmax2(hmax2(ph[4], ph[5]), hmax2(ph[6], ph[7]));
    half2v mx2 = hmax2(m0, m1);
    int mi = __builtin_bit_cast(int, mx2);
    mx2 = hmax2(mx2, __builtin_bit_cast(half2v, __shfl_xor(mi, 16)));
    mi = __builtin_bit_cast(int, mx2);
    mx2 = hmax2(mx2, __builtin_bit_cast(half2v, __shfl_xor(mi, 32)));
    const float mxf = fmaxf((float)mx2[0], (float)mx2[1]);
    // defer-max: only move the running max when growth exceeds 4 (log2 units);
    // deferred P values are bounded by 2^4=16, safe in f16 / f32 accum.
    const bool up = mxf > mrow + 4.0f;
    const float mn = up ? mxf : mrow;
    const float alpha = up ? exp2f(mrow - mn) : 1.0f;
    mrow = mn;

    const _Float16 mnh = (_Float16)mn;
    half2v mn2; mn2[0] = mnh; mn2[1] = mnh;
    half2v pe[8];
#pragma unroll
    for (int i = 0; i < 8; ++i)
      pe[i] = __builtin_elementwise_exp2(ph[i] - mn2);

    half2v one2; one2[0] = (_Float16)1.f; one2[1] = (_Float16)1.f;
    const fp16x2 one2p = __builtin_bit_cast(fp16x2, one2);
    float rs = 0.f;
#pragma unroll
    for (int i = 0; i < 8; ++i)
      rs = __builtin_amdgcn_fdot2(__builtin_bit_cast(fp16x2, pe[i]), one2p, rs, false);
    rs += __shfl_xor(rs, 16);
    rs += __shfl_xor(rs, 32);
    lrow = lrow * alpha + rs;

    if (__ballot(up)) {
      float alr[4];
#pragma unroll
      for (int r = 0; r < 4; ++r) alr[r] = __shfl(alpha, quad * 4 + r);
#pragma unroll
      for (int jb = 0; jb < 4; ++jb)
#pragma unroll
        for (int r = 0; r < 4; ++r) o16[jb][r] *= alr[r];
    }

    half4v ap[4];
#pragma unroll
    for (int jj = 0; jj < 4; ++jj)
      ap[jj] = __builtin_shufflevector(pe[jj * 2], pe[jj * 2 + 1], 0, 1, 2, 3);

    // O += P @ V : 16x16x16 MFMAs, P and V direct from registers.
#pragma unroll
    for (int jb = 0; jb < 4; ++jb) {
      half4v b0 = __builtin_shufflevector(v01[jb], v01[jb], 0, 1, 2, 3);
      half4v b1 = __builtin_shufflevector(v01[jb], v01[jb], 4, 5, 6, 7);
      half4v b2 = __builtin_shufflevector(v23[jb], v23[jb], 0, 1, 2, 3);
      half4v b3 = __builtin_shufflevector(v23[jb], v23[jb], 4, 5, 6, 7);
      o16[jb] = MFMA16(ap[0], b0, o16[jb]);
      o16[jb] = MFMA16(ap[1], b1, o16[jb]);
      o16[jb] = MFMA16(ap[2], b2, o16[jb]);
      o16[jb] = MFMA16(ap[3], b3, o16[jb]);
    }
  };

  for (int t = 0; t < 32; t += 2) {
    *(half8*)&Kb1[rr * 72 + cc] = kreg;
    if (t + 2 < 32) {
      kptr += 64 * HD;
      kreg = *(const half8*)kptr;
    }
    compute(Kb0, vbh + (size_t)t * 4096);
    __syncthreads();
    if (t + 2 < 32) {
      *(half8*)&Kb0[rr * 72 + cc] = kreg;
      if (t + 3 < 32) {
        kptr += 64 * HD;
        kreg = *(const half8*)kptr;
      }
    }
    compute(Kb1, vbh + (size_t)(t + 1) * 4096);
    __syncthreads();
  }

  float linv[4];
#pragma unroll
  for (int r = 0; r < 4; ++r) linv[r] = 1.0f / __shfl(lrow, quad * 4 + r);
#pragma unroll
  for (int jb = 0; jb < 4; ++jb) {
#pragma unroll
    for (int r = 0; r < 4; ++r) {
      const int row = q0 + wave * 16 + quad * 4 + r;
      attnb[(size_t)(b * S + row) * INNER + h * HD + jb * 16 + l16] =
          (_Float16)(o16[jb][r] * linv[r]);
    }
  }
}

// ---------------------------------------------------------------------------
extern "C" void kernel_launch(void* const* d_in, const int* in_sizes, int n_in,
                              void* d_out, int out_size, void* d_ws, size_t ws_size,
                              hipStream_t stream) {
  const float* hs    = (const float*)d_in[0];
  const float* rot   = (const float*)d_in[1];
  const float* w_qkv = (const float*)d_in[2];
  const float* b_qkv = (const float*)d_in[3];
  const float* nqw   = (const float*)d_in[4];
  const float* nkw   = (const float*)d_in[5];
  const float* w_out = (const float*)d_in[6];
  const float* b_out = (const float*)d_in[7];
  const float* hks   = (const float*)d_in[8];
  const int*   octx  = (const int*)d_in[9];

  _Float16* hsb   = (_Float16*)d_ws;                 // 0-8 MiB (attnb aliases)
  _Float16* attnb = hsb;
  _Float16* wqkvT = hsb   + (size_t)NTOK * DIM;      // 8-14 MiB
  _Float16* woutT = wqkvT + (size_t)QKVN * DIM;      // 14-16 MiB
  _Float16* qkvh  = woutT + (size_t)DIM * INNER;     // 16-40 MiB
  _Float16* q_h   = qkvh  + (size_t)NTOK * QKVN;     // 40-48 MiB
  _Float16* k_h   = q_h   + (size_t)B * NH * S * HD; // 48-56 MiB
  _Float16* vT    = k_h   + (size_t)B * NH * S * HD; // 56-64 MiB

  prep_all<<<3072, 256, 0, stream>>>(hs, w_qkv, w_out, hsb, wqkvT, woutT);

  gemm_bt<true, _Float16><<<dim3(QKVN / 128, NTOK / 128), 256, 0, stream>>>(
      hsb, wqkvT, b_qkv, qkvh, QKVN, DIM);

  post_all<<<5120, 256, 0, stream>>>(qkvh, rot, nqw, nkw, hks, octx, q_h, k_h, vT);

  attn_mfma<<<dim3(B * NH, S / 128), 512, 0, stream>>>(q_h, k_h, vT, attnb);

  gemm_bt<false, float><<<dim3(DIM / 128, NTOK / 128), 256, 0, stream>>>(
      attnb, woutT, b_out, (float*)d_out, DIM, INNER);
}

// Round 2
// 234.209 us; speedup vs baseline: 1.2485x; 1.2485x over previous
//
#include <hip/hip_runtime.h>
#include <math.h>

typedef float    floatx4 __attribute__((ext_vector_type(4)));
typedef _Float16 half8   __attribute__((ext_vector_type(8)));
typedef _Float16 half4v  __attribute__((ext_vector_type(4)));
typedef _Float16 half2v  __attribute__((ext_vector_type(2)));
typedef __fp16   fp16x2  __attribute__((ext_vector_type(2)));

constexpr int B    = 2;
constexpr int S    = 2048;
constexpr int NH   = 16;
constexpr int HD   = 64;
constexpr int DIM  = 1024;
constexpr int INNER = 1024;
constexpr int QKVN = 3072;
constexpr int NTOK = 4096;
constexpr float EPS = 1e-5f;
constexpr float MAX_SCALE = 10.0f;
constexpr float SCALE_LOG2E = 0.125f * 1.4426950408889634f;

#define MFMA16(a, b, c) __builtin_amdgcn_mfma_f32_16x16x16f16((a), (b), (c), 0, 0, 0)

__device__ __forceinline__ half2v pkrtz(float a, float b) {
  fp16x2 t = __builtin_amdgcn_cvt_pkrtz(a, b);
  return __builtin_bit_cast(half2v, t);
}
__device__ __forceinline__ half2v hmax2(half2v a, half2v b) {
  return __builtin_elementwise_max(a, b);
}

// Direct global->LDS DMA, 16 B per lane. LDS dest is wave-uniform base;
// HW writes at base + lane*16 (linear).
__device__ __forceinline__ void gl_lds16(const _Float16* g, _Float16* l) {
  __builtin_amdgcn_global_load_lds(
      (__attribute__((address_space(1))) void*)g,
      (__attribute__((address_space(3))) void*)l, 16, 0, 0);
}

// ---------------------------------------------------------------------------
// Fused prep: blockIdx [0,2048) fp32->fp16 convert of hs;
// [2048,2816) transpose w_qkv; [2816,3072) transpose w_out.
// ---------------------------------------------------------------------------
__device__ __forceinline__ void transpose_tile(const float* __restrict__ w,
                                               _Float16* __restrict__ wT,
                                               int K, int N, int k0, int n0,
                                               _Float16* T, int tid) {
#pragma unroll
  for (int i = 0; i < 4; ++i) {
    int id = tid + 256 * i;
    int r = id >> 4, c = id & 15;
    float4 v = *(const float4*)&w[(size_t)(k0 + r) * N + n0 + c * 4];
    half4v s; s[0] = (_Float16)v.x; s[1] = (_Float16)v.y;
    s[2] = (_Float16)v.z; s[3] = (_Float16)v.w;
    *(half4v*)&T[r * 72 + c * 4] = s;
  }
  __syncthreads();
#pragma unroll
  for (int i = 0; i < 2; ++i) {
    int id = tid + 256 * i;
    int n = id >> 3, cs = id & 7;
    half8 o;
#pragma unroll
    for (int jj = 0; jj < 8; ++jj) o[jj] = T[(cs * 8 + jj) * 72 + n];
    *(half8*)&wT[(size_t)(n0 + n) * K + k0 + cs * 8] = o;
  }
}

__global__ __launch_bounds__(256)
void prep_all(const float* __restrict__ hs, const float* __restrict__ w_qkv,
              const float* __restrict__ w_out, _Float16* __restrict__ hsb,
              _Float16* __restrict__ wqkvT, _Float16* __restrict__ woutT) {
  __shared__ _Float16 T[64 * 72];
  const int bx = blockIdx.x, tid = threadIdx.x;
  if (bx < 2048) {
    int id = bx * 256 + tid;
    const float4 a = ((const float4*)hs)[id * 2];
    const float4 b = ((const float4*)hs)[id * 2 + 1];
    half8 o;
    o[0] = (_Float16)a.x; o[1] = (_Float16)a.y; o[2] = (_Float16)a.z; o[3] = (_Float16)a.w;
    o[4] = (_Float16)b.x; o[5] = (_Float16)b.y; o[6] = (_Float16)b.z; o[7] = (_Float16)b.w;
    ((half8*)hsb)[id] = o;
  } else if (bx < 2816) {
    int id = bx - 2048;
    transpose_tile(w_qkv, wqkvT, DIM, QKVN, (id / 48) * 64, (id % 48) * 64, T, tid);
  } else {
    int id = bx - 2816;
    transpose_tile(w_out, woutT, INNER, DIM, (id / 16) * 64, (id % 16) * 64, T, tid);
  }
}

// ---------------------------------------------------------------------------
// fp16 MFMA GEMM: global_load_lds width-16 staging, BK=64, double-buffered
// LDS with 2-phase schedule (issue next tile's DMA BEFORE computing current;
// one barrier per K-step drains it). XOR source/read swizzle (T2, rule #21):
//   LDS[r][chunk c] = G[r][chunk c ^ (r&7)]   (chunks of 16 B)
// ---------------------------------------------------------------------------
template<bool OUT_F16, typename OutT>
__global__ __launch_bounds__(256)
void gemm_bt(const _Float16* __restrict__ A, const _Float16* __restrict__ BT,
             const float* __restrict__ bias, OutT* __restrict__ C, int N, int K) {
  __shared__ _Float16 As[2][128 * 64];
  __shared__ _Float16 Bs[2][128 * 64];
  const int tid = threadIdx.x;
  const int wave = tid >> 6, lane = tid & 63, quad = lane >> 4, l16 = lane & 15;
  const int wm = wave >> 1, wn = wave & 1;
  const int m0 = blockIdx.y * 128, n0 = blockIdx.x * 128;

  // staging geometry: instr i of wave w covers rows i*32 + w*8 .. +8.
  // lane l -> row + (l>>3), dest 16B-chunk c = l&7; source chunk = c ^ (row&7).
  const int srow = lane >> 3;
  const int scolh = ((lane & 7) ^ srow) * 8;   // row&7 == srow (row bases are x8)
  const _Float16* Ag = A  + (size_t)(m0 + wave * 8 + srow) * K + scolh;
  const _Float16* Bg = BT + (size_t)(n0 + wave * 8 + srow) * K + scolh;

  auto stage = [&](int k0, int buf) {
#pragma unroll
    for (int i = 0; i < 4; ++i) {
      gl_lds16(Ag + (size_t)i * 32 * K + k0, &As[buf][(i * 4 + wave) * 512]);
      gl_lds16(Bg + (size_t)i * 32 * K + k0, &Bs[buf][(i * 4 + wave) * 512]);
    }
  };

  floatx4 acc[4][4] = {};
  const int rx = l16 & 7;

  stage(0, 0);
  __syncthreads();
  int cur = 0;
  for (int k0 = 0; k0 < K; k0 += 64) {
    if (k0 + 64 < K) stage(k0 + 64, cur ^ 1);   // async; flies under MFMAs
#pragma unroll
    for (int ks = 0; ks < 2; ++ks) {
      half8 a[4], b[4];
#pragma unroll
      for (int i = 0; i < 4; ++i)
        a[i] = *(const half8*)&As[cur][(wm * 64 + i * 16 + l16) * 64 + (((ks * 4 + quad) ^ rx) * 8)];
#pragma unroll
      for (int j = 0; j < 4; ++j)
        b[j] = *(const half8*)&Bs[cur][(wn * 64 + j * 16 + l16) * 64 + (((ks * 4 + quad) ^ rx) * 8)];
#pragma unroll
      for (int i = 0; i < 4; ++i)
#pragma unroll
        for (int j = 0; j < 4; ++j)
          acc[i][j] = __builtin_amdgcn_mfma_f32_16x16x32_f16(a[i], b[j], acc[i][j], 0, 0, 0);
    }
    __syncthreads();   // drains vmcnt(0): next buffer staged + reads done
    cur ^= 1;
  }

  const int rb = m0 + wm * 64 + quad * 4;
  const int cb = n0 + wn * 64 + l16;
#pragma unroll
  for (int j = 0; j < 4; ++j) {
    const float bj = bias[cb + j * 16];
#pragma unroll
    for (int i = 0; i < 4; ++i) {
#pragma unroll
      for (int r = 0; r < 4; ++r) {
        float v = acc[i][j][r] + bj;
        size_t idx = (size_t)(rb + i * 16 + r) * N + cb + j * 16;
        if constexpr (OUT_F16) C[idx] = (_Float16)v; else C[idx] = v;
      }
    }
  }
}

// ---------------------------------------------------------------------------
// Fused post: blockIdx [0,4096) = per-token RMSNorm+rotary+hist-scale;
// [4096,5120) = V transpose/swizzle tiles (fragment order for PV MFMAs).
// ---------------------------------------------------------------------------
__global__ __launch_bounds__(256)
void post_all(const _Float16* __restrict__ qkvh, const float* __restrict__ rot,
              const float* __restrict__ nqw, const float* __restrict__ nkw,
              const float* __restrict__ hks, const int* __restrict__ octx,
              _Float16* __restrict__ qo_, _Float16* __restrict__ ko_,
              _Float16* __restrict__ vt) {
  __shared__ __align__(16) char arena[64 * 72 * 2];
  const int tid = threadIdx.x;
  if (blockIdx.x < 4096) {
    float* red = (float*)arena;
    const int token = blockIdx.x;
    const int b = token >> 11, spos = token & (S - 1);
    const _Float16* qrow = qkvh + (size_t)token * QKVN;
    const _Float16* krow = qrow + INNER;
    const float* r = rot + (size_t)token * (2 * HD);

    const int e0 = tid * 4;
    half4v qs = *(const half4v*)(qrow + e0);
    half4v ks = *(const half4v*)(krow + e0);
    float q4[4], k4[4];
#pragma unroll
    for (int i = 0; i < 4; ++i) { q4[i] = (float)qs[i]; k4[i] = (float)ks[i]; }

    float sq = 0.f, sk = 0.f;
#pragma unroll
    for (int i = 0; i < 4; ++i) { sq += q4[i] * q4[i]; sk += k4[i] * k4[i]; }
#pragma unroll
    for (int msk = 1; msk < 64; msk <<= 1) {
      sq += __shfl_xor(sq, msk);
      sk += __shfl_xor(sk, msk);
    }
    const int wv = tid >> 6;
    if ((tid & 63) == 0) { red[wv] = sq; red[4 + wv] = sk; }
    __syncthreads();
    sq = red[0] + red[1] + red[2] + red[3];
    sk = red[4] + red[5] + red[6] + red[7];

    const float qinv = 1.0f / sqrtf(sq * (1.0f / INNER) + EPS);
    const float kinv = 1.0f / sqrtf(sk * (1.0f / INNER) + EPS);

#pragma unroll
    for (int i = 0; i < 4; ++i) {
      q4[i] = q4[i] * qinv * nqw[e0 + i];
      k4[i] = k4[i] * kinv * nkw[e0 + i];
    }

    const int h = e0 >> 6, d0 = e0 & (HD - 1);
    const float c0 = r[d0],     s0 = r[HD + d0 + 1];
    const float c1 = r[d0 + 2], s1 = r[HD + d0 + 3];

    float qo[4], ko[4];
    qo[0] = q4[0] * c0 - q4[1] * s0;
    qo[1] = q4[0] * s0 + q4[1] * c0;
    qo[2] = q4[2] * c1 - q4[3] * s1;
    qo[3] = q4[2] * s1 + q4[3] * c1;
    ko[0] = k4[0] * c0 - k4[1] * s0;
    ko[1] = k4[0] * s0 + k4[1] * c0;
    ko[2] = k4[2] * c1 - k4[3] * s1;
    ko[3] = k4[2] * s1 + k4[3] * c1;

    const int hist = S - octx[0];
    if (hist > 0 && spos < hist) {
      const float sig = 1.0f / (1.0f + expf(-hks[h]));
      const float sc = 1.0f + sig * (MAX_SCALE - 1.0f);
#pragma unroll
      for (int i = 0; i < 4; ++i) ko[i] *= sc;
    }

    half4v qo4, ko4;
#pragma unroll
    for (int i = 0; i < 4; ++i) {
      qo4[i] = (_Float16)(qo[i] * SCALE_LOG2E);
      ko4[i] = (_Float16)ko[i];
    }
    const size_t obase = ((size_t)(b * NH + h) * S + spos) * HD + d0;
    *(half4v*)(qo_ + obase) = qo4;
    *(half4v*)(ko_ + obase) = ko4;
  } else {
    _Float16* T = (_Float16*)arena;
    const int id = blockIdx.x - 4096;
    const int bh = id & 31, kt = id >> 5;
    const int b = bh >> 4, h = bh & 15;
    const int s0 = kt * 64;
#pragma unroll
    for (int i = 0; i < 2; ++i) {
      int id2 = tid + 256 * i;
      int s = id2 >> 3, c = id2 & 7;
      *(half8*)&T[s * 72 + c * 8] =
          *(const half8*)&qkvh[(size_t)(b * S + s0 + s) * QKVN + 2 * INNER + h * HD + c * 8];
    }
    __syncthreads();
    _Float16* orow = vt + ((size_t)bh * 32 + kt) * 64 * 64;
#pragma unroll
    for (int i = 0; i < 4; ++i) {
      int id2 = tid + 256 * i;
      int d = id2 >> 4, g = id2 & 15;
      int quad = g >> 2, jj = g & 3;
      half4v o;
#pragma unroll
      for (int k = 0; k < 4; ++k) o[k] = T[(jj * 16 + quad * 4 + k) * 72 + d];
      *(half4v*)&orow[d * 64 + g * 4] = o;
    }
  }
}

// ---------------------------------------------------------------------------
// MFMA flash attention: 256 thr = 4 waves, each wave owns 32 Q-rows (two
// 16-row fragment groups g=0,1). Every K/V fragment read from LDS feeds 2x
// the MFMAs of the R0 version -> LDS read traffic halved (~2.1 -> ~1.05 GB).
// K,V double-buffered in LDS with register prefetch. Packed-f16 softmax in
// log2 domain with defer-max (THR=4).
// ---------------------------------------------------------------------------
__global__ __launch_bounds__(256)
void attn_mfma(const _Float16* __restrict__ qb, const _Float16* __restrict__ kb,
               const _Float16* __restrict__ vt, _Float16* __restrict__ attnb) {
  __shared__ _Float16 Kb0[64 * 72], Vb0[64 * 72];
  __shared__ _Float16 Kb1[64 * 72], Vb1[64 * 72];
  const int bh = blockIdx.x;
  const int b = bh >> 4, h = bh & 15;
  const int q0 = blockIdx.y * 128;
  const int tid = threadIdx.x;
  const int wave = tid >> 6, lane = tid & 63, quad = lane >> 4, l16 = lane & 15;

  const _Float16* qbh = qb + (size_t)bh * S * HD;
  const _Float16* kbh = kb + (size_t)bh * S * HD;
  const _Float16* vbh = vt + (size_t)bh * S * HD;

  half8 aq[2][2];
#pragma unroll
  for (int g = 0; g < 2; ++g)
#pragma unroll
    for (int ks = 0; ks < 2; ++ks)
      aq[g][ks] = *(const half8*)&qbh[(size_t)(q0 + wave * 32 + g * 16 + l16) * HD + ks * 32 + quad * 8];

  // staging: 256 threads cover 32 rows x 64 cols per instruction; two each.
  const int rr = tid >> 3, cc = (tid & 7) * 8;
  const _Float16* kpA = kbh + (size_t)rr * HD + cc;
  const _Float16* kpB = kbh + (size_t)(rr + 32) * HD + cc;
  const _Float16* vpA = vbh + (size_t)rr * 64 + cc;
  const _Float16* vpB = vbh + (size_t)(rr + 32) * 64 + cc;

  half8 kA = *(const half8*)kpA, kB = *(const half8*)kpB;
  half8 vA = *(const half8*)vpA, vB = *(const half8*)vpB;
  *(half8*)&Kb0[rr * 72 + cc] = kA;
  *(half8*)&Kb0[(rr + 32) * 72 + cc] = kB;
  *(half8*)&Vb0[rr * 72 + cc] = vA;
  *(half8*)&Vb0[(rr + 32) * 72 + cc] = vB;
  kpA += 64 * HD; kpB += 64 * HD; vpA += 64 * 64; vpB += 64 * 64;
  kA = *(const half8*)kpA; kB = *(const half8*)kpB;
  vA = *(const half8*)vpA; vB = *(const half8*)vpB;
  __syncthreads();

  floatx4 o16[2][4] = {};
  float mrow[2] = {-INFINITY, -INFINITY};
  float lrow[2] = {0.f, 0.f};

  auto compute = [&](const _Float16* Kp, const _Float16* Vp) {
    // S^T = K @ Q^T for both q-groups; each K-frag LDS read feeds 2 MFMAs.
    floatx4 sc[2][4] = {};
#pragma unroll
    for (int jj = 0; jj < 4; ++jj) {
#pragma unroll
      for (int ks = 0; ks < 2; ++ks) {
        half8 ak = *(const half8*)&Kp[(jj * 16 + l16) * 72 + ks * 32 + quad * 8];
        sc[0][jj] = __builtin_amdgcn_mfma_f32_16x16x32_f16(ak, aq[0][ks], sc[0][jj], 0, 0, 0);
        sc[1][jj] = __builtin_amdgcn_mfma_f32_16x16x32_f16(ak, aq[1][ks], sc[1][jj], 0, 0, 0);
      }
    }

    half4v ap[2][4];
#pragma unroll
    for (int g = 0; g < 2; ++g) {
      // ---- packed f16 online softmax (log2 domain; scale pre-folded in q) ----
      half2v ph[8];
#pragma unroll
      for (int jj = 0; jj < 4; ++jj) {
        ph[jj * 2]     = pkrtz(sc[g][jj][0], sc[g][jj][1]);
        ph[jj * 2 + 1] = pkrtz(sc[g][jj][2], sc[g][jj][3]);
      }
      half2v m0 = hmax2(hmax2(ph[0], ph[1]), hmax2(ph[2], ph[3]));
      half2v m1 = hmax2(hmax2(ph[4], ph[5]), hmax2(ph[6], ph[7]));
      half2v mx2 = hmax2(m0, m1);
      int mi = __builtin_bit_cast(int, mx2);
      mx2 = hmax2(mx2, __builtin_bit_cast(half2v, __shfl_xor(mi, 16)));
      mi = __builtin_bit_cast(int, mx2);
      mx2 = hmax2(mx2, __builtin_bit_cast(half2v, __shfl_xor(mi, 32)));
      const float mxf = fmaxf((float)mx2[0], (float)mx2[1]);
      // defer-max: move running max only on growth > 4 (log2 units); deferred
      // P bounded by 2^4=16, safe in f16 / f32 accum.
      const bool up = mxf > mrow[g] + 4.0f;
      const float mn = up ? mxf : mrow[g];
      const float alpha = up ? exp2f(mrow[g] - mn) : 1.0f;
      mrow[g] = mn;

      const _Float16 mnh = (_Float16)mn;
      half2v mn2; mn2[0] = mnh; mn2[1] = mnh;
      half2v pe[8];
#pragma unroll
      for (int i = 0; i < 8; ++i)
        pe[i] = __builtin_elementwise_exp2(ph[i] - mn2);

      half2v one2; one2[0] = (_Float16)1.f; one2[1] = (_Float16)1.f;
      const fp16x2 one2p = __builtin_bit_cast(fp16x2, one2);
      float rs = 0.f;
#pragma unroll
      for (int i = 0; i < 8; ++i)
        rs = __builtin_amdgcn_fdot2(__builtin_bit_cast(fp16x2, pe[i]), one2p, rs, false);
      rs += __shfl_xor(rs, 16);
      rs += __shfl_xor(rs, 32);
      lrow[g] = lrow[g] * alpha + rs;

      if (__ballot(up)) {
        float alr[4];
#pragma unroll
        for (int r = 0; r < 4; ++r) alr[r] = __shfl(alpha, quad * 4 + r);
#pragma unroll
        for (int jb = 0; jb < 4; ++jb)
#pragma unroll
          for (int r = 0; r < 4; ++r) o16[g][jb][r] *= alr[r];
      }

#pragma unroll
      for (int jj = 0; jj < 4; ++jj)
        ap[g][jj] = __builtin_shufflevector(pe[jj * 2], pe[jj * 2 + 1], 0, 1, 2, 3);
    }

    // O += P @ V; each V-frag LDS read feeds both q-groups (8 MFMAs).
#pragma unroll
    for (int jb = 0; jb < 4; ++jb) {
      half8 v01 = *(const half8*)&Vp[(jb * 16 + l16) * 72 + quad * 16];
      half8 v23 = *(const half8*)&Vp[(jb * 16 + l16) * 72 + quad * 16 + 8];
      half4v b0 = __builtin_shufflevector(v01, v01, 0, 1, 2, 3);
      half4v b1 = __builtin_shufflevector(v01, v01, 4, 5, 6, 7);
      half4v b2 = __builtin_shufflevector(v23, v23, 0, 1, 2, 3);
      half4v b3 = __builtin_shufflevector(v23, v23, 4, 5, 6, 7);
#pragma unroll
      for (int g = 0; g < 2; ++g) {
        o16[g][jb] = MFMA16(ap[g][0], b0, o16[g][jb]);
        o16[g][jb] = MFMA16(ap[g][1], b1, o16[g][jb]);
        o16[g][jb] = MFMA16(ap[g][2], b2, o16[g][jb]);
        o16[g][jb] = MFMA16(ap[g][3], b3, o16[g][jb]);
      }
    }
  };

  for (int t = 0; t < 32; t += 2) {
    *(half8*)&Kb1[rr * 72 + cc] = kA;
    *(half8*)&Kb1[(rr + 32) * 72 + cc] = kB;
    *(half8*)&Vb1[rr * 72 + cc] = vA;
    *(half8*)&Vb1[(rr + 32) * 72 + cc] = vB;
    if (t + 2 < 32) {
      kpA += 64 * HD; kpB += 64 * HD; vpA += 64 * 64; vpB += 64 * 64;
      kA = *(const half8*)kpA; kB = *(const half8*)kpB;
      vA = *(const half8*)vpA; vB = *(const half8*)vpB;
    }
    compute(Kb0, Vb0);
    __syncthreads();
    if (t + 2 < 32) {
      *(half8*)&Kb0[rr * 72 + cc] = kA;
      *(half8*)&Kb0[(rr + 32) * 72 + cc] = kB;
      *(half8*)&Vb0[rr * 72 + cc] = vA;
      *(half8*)&Vb0[(rr + 32) * 72 + cc] = vB;
      if (t + 3 < 32) {
        kpA += 64 * HD; kpB += 64 * HD; vpA += 64 * 64; vpB += 64 * 64;
        kA = *(const half8*)kpA; kB = *(const half8*)kpB;
        vA = *(const half8*)vpA; vB = *(const half8*)vpB;
      }
    }
    compute(Kb1, Vb1);
    __syncthreads();
  }

#pragma unroll
  for (int g = 0; g < 2; ++g) {
    float linv[4];
#pragma unroll
    for (int r = 0; r < 4; ++r) linv[r] = 1.0f / __shfl(lrow[g], quad * 4 + r);
#pragma unroll
    for (int jb = 0; jb < 4; ++jb) {
#pragma unroll
      for (int r = 0; r < 4; ++r) {
        const int row = q0 + wave * 32 + g * 16 + quad * 4 + r;
        attnb[(size_t)(b * S + row) * INNER + h * HD + jb * 16 + l16] =
            (_Float16)(o16[g][jb][r] * linv[r]);
      }
    }
  }
}

// ---------------------------------------------------------------------------
extern "C" void kernel_launch(void* const* d_in, const int* in_sizes, int n_in,
                              void* d_out, int out_size, void* d_ws, size_t ws_size,
                              hipStream_t stream) {
  const float* hs    = (const float*)d_in[0];
  const float* rot   = (const float*)d_in[1];
  const float* w_qkv = (const float*)d_in[2];
  const float* b_qkv = (const float*)d_in[3];
  const float* nqw   = (const float*)d_in[4];
  const float* nkw   = (const float*)d_in[5];
  const float* w_out = (const float*)d_in[6];
  const float* b_out = (const float*)d_in[7];
  const float* hks   = (const float*)d_in[8];
  const int*   octx  = (const int*)d_in[9];

  _Float16* hsb   = (_Float16*)d_ws;                 // 0-8 MiB (attnb aliases)
  _Float16* attnb = hsb;
  _Float16* wqkvT = hsb   + (size_t)NTOK * DIM;      // 8-14 MiB
  _Float16* woutT = wqkvT + (size_t)QKVN * DIM;      // 14-16 MiB
  _Float16* qkvh  = woutT + (size_t)DIM * INNER;     // 16-40 MiB
  _Float16* q_h   = qkvh  + (size_t)NTOK * QKVN;     // 40-48 MiB
  _Float16* k_h   = q_h   + (size_t)B * NH * S * HD; // 48-56 MiB
  _Float16* vT    = k_h   + (size_t)B * NH * S * HD; // 56-64 MiB

  prep_all<<<3072, 256, 0, stream>>>(hs, w_qkv, w_out, hsb, wqkvT, woutT);

  gemm_bt<true, _Float16><<<dim3(QKVN / 128, NTOK / 128), 256, 0, stream>>>(
      hsb, wqkvT, b_qkv, qkvh, QKVN, DIM);

  post_all<<<5120, 256, 0, stream>>>(qkvh, rot, nqw, nkw, hks, octx, q_h, k_h, vT);

  attn_mfma<<<dim3(B * NH, S / 128), 256, 0, stream>>>(q_h, k_h, vT, attnb);

  gemm_bt<false, float><<<dim3(DIM / 128, NTOK / 128), 256, 0, stream>>>(
      attnb, woutT, b_out, (float*)d_out, DIM, INNER);
}

// Round 3
// 215.590 us; speedup vs baseline: 1.3564x; 1.0864x over previous
//
#include <hip/hip_runtime.h>
#include <math.h>

typedef float    floatx4 __attribute__((ext_vector_type(4)));
typedef _Float16 half8   __attribute__((ext_vector_type(8)));
typedef _Float16 half4v  __attribute__((ext_vector_type(4)));
typedef _Float16 half2v  __attribute__((ext_vector_type(2)));
typedef __fp16   fp16x2  __attribute__((ext_vector_type(2)));

constexpr int B    = 2;
constexpr int S    = 2048;
constexpr int NH   = 16;
constexpr int HD   = 64;
constexpr int DIM  = 1024;
constexpr int INNER = 1024;
constexpr int QKVN = 3072;
constexpr int NTOK = 4096;
constexpr float EPS = 1e-5f;
constexpr float MAX_SCALE = 10.0f;
constexpr float SCALE_LOG2E = 0.125f * 1.4426950408889634f;

#define MFMA16(a, b, c) __builtin_amdgcn_mfma_f32_16x16x16f16((a), (b), (c), 0, 0, 0)
#define MFMA32(a, b, c) __builtin_amdgcn_mfma_f32_16x16x32_f16((a), (b), (c), 0, 0, 0)

__device__ __forceinline__ half2v pkrtz(float a, float b) {
  fp16x2 t = __builtin_amdgcn_cvt_pkrtz(a, b);
  return __builtin_bit_cast(half2v, t);
}
__device__ __forceinline__ half2v hmax2(half2v a, half2v b) {
  return __builtin_elementwise_max(a, b);
}

// Direct global->LDS DMA, 16 B per lane. LDS dest is wave-uniform base;
// HW writes at base + lane*16 (linear).
__device__ __forceinline__ void gl_lds16(const _Float16* g, _Float16* l) {
  __builtin_amdgcn_global_load_lds(
      (__attribute__((address_space(1))) void*)g,
      (__attribute__((address_space(3))) void*)l, 16, 0, 0);
}

// ---------------------------------------------------------------------------
// Fused prep: blockIdx [0,2048) fp32->fp16 convert of hs;
// [2048,2816) transpose w_qkv; [2816,3072) transpose w_out.
// ---------------------------------------------------------------------------
__device__ __forceinline__ void transpose_tile(const float* __restrict__ w,
                                               _Float16* __restrict__ wT,
                                               int K, int N, int k0, int n0,
                                               _Float16* T, int tid) {
#pragma unroll
  for (int i = 0; i < 4; ++i) {
    int id = tid + 256 * i;
    int r = id >> 4, c = id & 15;
    float4 v = *(const float4*)&w[(size_t)(k0 + r) * N + n0 + c * 4];
    half4v s; s[0] = (_Float16)v.x; s[1] = (_Float16)v.y;
    s[2] = (_Float16)v.z; s[3] = (_Float16)v.w;
    *(half4v*)&T[r * 72 + c * 4] = s;
  }
  __syncthreads();
#pragma unroll
  for (int i = 0; i < 2; ++i) {
    int id = tid + 256 * i;
    int n = id >> 3, cs = id & 7;
    half8 o;
#pragma unroll
    for (int jj = 0; jj < 8; ++jj) o[jj] = T[(cs * 8 + jj) * 72 + n];
    *(half8*)&wT[(size_t)(n0 + n) * K + k0 + cs * 8] = o;
  }
}

__global__ __launch_bounds__(256)
void prep_all(const float* __restrict__ hs, const float* __restrict__ w_qkv,
              const float* __restrict__ w_out, _Float16* __restrict__ hsb,
              _Float16* __restrict__ wqkvT, _Float16* __restrict__ woutT) {
  __shared__ _Float16 T[64 * 72];
  const int bx = blockIdx.x, tid = threadIdx.x;
  if (bx < 2048) {
    int id = bx * 256 + tid;
    const float4 a = ((const float4*)hs)[id * 2];
    const float4 b = ((const float4*)hs)[id * 2 + 1];
    half8 o;
    o[0] = (_Float16)a.x; o[1] = (_Float16)a.y; o[2] = (_Float16)a.z; o[3] = (_Float16)a.w;
    o[4] = (_Float16)b.x; o[5] = (_Float16)b.y; o[6] = (_Float16)b.z; o[7] = (_Float16)b.w;
    ((half8*)hsb)[id] = o;
  } else if (bx < 2816) {
    int id = bx - 2048;
    transpose_tile(w_qkv, wqkvT, DIM, QKVN, (id / 48) * 64, (id % 48) * 64, T, tid);
  } else {
    int id = bx - 2816;
    transpose_tile(w_out, woutT, INNER, DIM, (id / 16) * 64, (id % 16) * 64, T, tid);
  }
}

// ---------------------------------------------------------------------------
// fp16 MFMA GEMM: global_load_lds width-16 staging, BK=64, double-buffered
// LDS with 2-phase schedule (issue next tile's DMA BEFORE computing current;
// one barrier per K-step drains it). XOR source/read swizzle (T2, rule #21).
// (unchanged from R2)
// ---------------------------------------------------------------------------
template<bool OUT_F16, typename OutT>
__global__ __launch_bounds__(256)
void gemm_bt(const _Float16* __restrict__ A, const _Float16* __restrict__ BT,
             const float* __restrict__ bias, OutT* __restrict__ C, int N, int K) {
  __shared__ _Float16 As[2][128 * 64];
  __shared__ _Float16 Bs[2][128 * 64];
  const int tid = threadIdx.x;
  const int wave = tid >> 6, lane = tid & 63, quad = lane >> 4, l16 = lane & 15;
  const int wm = wave >> 1, wn = wave & 1;
  const int m0 = blockIdx.y * 128, n0 = blockIdx.x * 128;

  const int srow = lane >> 3;
  const int scolh = ((lane & 7) ^ srow) * 8;
  const _Float16* Ag = A  + (size_t)(m0 + wave * 8 + srow) * K + scolh;
  const _Float16* Bg = BT + (size_t)(n0 + wave * 8 + srow) * K + scolh;

  auto stage = [&](int k0, int buf) {
#pragma unroll
    for (int i = 0; i < 4; ++i) {
      gl_lds16(Ag + (size_t)i * 32 * K + k0, &As[buf][(i * 4 + wave) * 512]);
      gl_lds16(Bg + (size_t)i * 32 * K + k0, &Bs[buf][(i * 4 + wave) * 512]);
    }
  };

  floatx4 acc[4][4] = {};
  const int rx = l16 & 7;

  stage(0, 0);
  __syncthreads();
  int cur = 0;
  for (int k0 = 0; k0 < K; k0 += 64) {
    if (k0 + 64 < K) stage(k0 + 64, cur ^ 1);   // async; flies under MFMAs
#pragma unroll
    for (int ks = 0; ks < 2; ++ks) {
      half8 a[4], b[4];
#pragma unroll
      for (int i = 0; i < 4; ++i)
        a[i] = *(const half8*)&As[cur][(wm * 64 + i * 16 + l16) * 64 + (((ks * 4 + quad) ^ rx) * 8)];
#pragma unroll
      for (int j = 0; j < 4; ++j)
        b[j] = *(const half8*)&Bs[cur][(wn * 64 + j * 16 + l16) * 64 + (((ks * 4 + quad) ^ rx) * 8)];
#pragma unroll
      for (int i = 0; i < 4; ++i)
#pragma unroll
        for (int j = 0; j < 4; ++j)
          acc[i][j] = MFMA32(a[i], b[j], acc[i][j]);
    }
    __syncthreads();
    cur ^= 1;
  }

  const int rb = m0 + wm * 64 + quad * 4;
  const int cb = n0 + wn * 64 + l16;
#pragma unroll
  for (int j = 0; j < 4; ++j) {
    const float bj = bias[cb + j * 16];
#pragma unroll
    for (int i = 0; i < 4; ++i) {
#pragma unroll
      for (int r = 0; r < 4; ++r) {
        float v = acc[i][j][r] + bj;
        size_t idx = (size_t)(rb + i * 16 + r) * N + cb + j * 16;
        if constexpr (OUT_F16) C[idx] = (_Float16)v; else C[idx] = v;
      }
    }
  }
}

// ---------------------------------------------------------------------------
// Fused post: blockIdx [0,4096) = per-token RMSNorm+rotary+hist-scale;
// [4096,5120) = V transpose/swizzle tiles (fragment order for PV MFMAs).
// ---------------------------------------------------------------------------
__global__ __launch_bounds__(256)
void post_all(const _Float16* __restrict__ qkvh, const float* __restrict__ rot,
              const float* __restrict__ nqw, const float* __restrict__ nkw,
              const float* __restrict__ hks, const int* __restrict__ octx,
              _Float16* __restrict__ qo_, _Float16* __restrict__ ko_,
              _Float16* __restrict__ vt) {
  __shared__ __align__(16) char arena[64 * 72 * 2];
  const int tid = threadIdx.x;
  if (blockIdx.x < 4096) {
    float* red = (float*)arena;
    const int token = blockIdx.x;
    const int b = token >> 11, spos = token & (S - 1);
    const _Float16* qrow = qkvh + (size_t)token * QKVN;
    const _Float16* krow = qrow + INNER;
    const float* r = rot + (size_t)token * (2 * HD);

    const int e0 = tid * 4;
    half4v qs = *(const half4v*)(qrow + e0);
    half4v ks = *(const half4v*)(krow + e0);
    float q4[4], k4[4];
#pragma unroll
    for (int i = 0; i < 4; ++i) { q4[i] = (float)qs[i]; k4[i] = (float)ks[i]; }

    float sq = 0.f, sk = 0.f;
#pragma unroll
    for (int i = 0; i < 4; ++i) { sq += q4[i] * q4[i]; sk += k4[i] * k4[i]; }
#pragma unroll
    for (int msk = 1; msk < 64; msk <<= 1) {
      sq += __shfl_xor(sq, msk);
      sk += __shfl_xor(sk, msk);
    }
    const int wv = tid >> 6;
    if ((tid & 63) == 0) { red[wv] = sq; red[4 + wv] = sk; }
    __syncthreads();
    sq = red[0] + red[1] + red[2] + red[3];
    sk = red[4] + red[5] + red[6] + red[7];

    const float qinv = 1.0f / sqrtf(sq * (1.0f / INNER) + EPS);
    const float kinv = 1.0f / sqrtf(sk * (1.0f / INNER) + EPS);

#pragma unroll
    for (int i = 0; i < 4; ++i) {
      q4[i] = q4[i] * qinv * nqw[e0 + i];
      k4[i] = k4[i] * kinv * nkw[e0 + i];
    }

    const int h = e0 >> 6, d0 = e0 & (HD - 1);
    const float c0 = r[d0],     s0 = r[HD + d0 + 1];
    const float c1 = r[d0 + 2], s1 = r[HD + d0 + 3];

    float qo[4], ko[4];
    qo[0] = q4[0] * c0 - q4[1] * s0;
    qo[1] = q4[0] * s0 + q4[1] * c0;
    qo[2] = q4[2] * c1 - q4[3] * s1;
    qo[3] = q4[2] * s1 + q4[3] * c1;
    ko[0] = k4[0] * c0 - k4[1] * s0;
    ko[1] = k4[0] * s0 + k4[1] * c0;
    ko[2] = k4[2] * c1 - k4[3] * s1;
    ko[3] = k4[2] * s1 + k4[3] * c1;

    const int hist = S - octx[0];
    if (hist > 0 && spos < hist) {
      const float sig = 1.0f / (1.0f + expf(-hks[h]));
      const float sc = 1.0f + sig * (MAX_SCALE - 1.0f);
#pragma unroll
      for (int i = 0; i < 4; ++i) ko[i] *= sc;
    }

    half4v qo4, ko4;
#pragma unroll
    for (int i = 0; i < 4; ++i) {
      qo4[i] = (_Float16)(qo[i] * SCALE_LOG2E);
      ko4[i] = (_Float16)ko[i];
    }
    const size_t obase = ((size_t)(b * NH + h) * S + spos) * HD + d0;
    *(half4v*)(qo_ + obase) = qo4;
    *(half4v*)(ko_ + obase) = ko4;
  } else {
    _Float16* T = (_Float16*)arena;
    const int id = blockIdx.x - 4096;
    const int bh = id & 31, kt = id >> 5;
    const int b = bh >> 4, h = bh & 15;
    const int s0 = kt * 64;
#pragma unroll
    for (int i = 0; i < 2; ++i) {
      int id2 = tid + 256 * i;
      int s = id2 >> 3, c = id2 & 7;
      *(half8*)&T[s * 72 + c * 8] =
          *(const half8*)&qkvh[(size_t)(b * S + s0 + s) * QKVN + 2 * INNER + h * HD + c * 8];
    }
    __syncthreads();
    _Float16* orow = vt + ((size_t)bh * 32 + kt) * 64 * 64;
#pragma unroll
    for (int i = 0; i < 4; ++i) {
      int id2 = tid + 256 * i;
      int d = id2 >> 4, g = id2 & 15;
      int quad = g >> 2, jj = g & 3;
      half4v o;
#pragma unroll
      for (int k = 0; k < 4; ++k) o[k] = T[(jj * 16 + quad * 4 + k) * 72 + d];
      *(half4v*)&orow[d * 64 + g * 4] = o;
    }
  }
}

// ---------------------------------------------------------------------------
// MFMA flash attention, R3: 512 thr = 8 waves, 16 Q-rows/wave (R0 geometry,
// full occupancy) AND two K-tiles per barrier interval (R2's ILP win):
//  - 2 independent QK/exp/dot chains per wave iteration (SIMD interleaves)
//  - ONE max-update / alpha / rescale / shuffle-pair per 2 tiles
//  - one barrier per 2 tiles
// LDS: pitch-64 linear + XOR-chunk swizzle (write & read XOR by row&7) ->
// 2-way (free) bank access, replacing the 72-pitch 2cyc/read overhead.
// 2 pairs x (K+V) x 64x64 f16 = 64 KB -> 2 blocks/CU (= grid supply).
// ---------------------------------------------------------------------------
__global__ __launch_bounds__(512, 4)
void attn_mfma(const _Float16* __restrict__ qb, const _Float16* __restrict__ kb,
               const _Float16* __restrict__ vt, _Float16* __restrict__ attnb) {
  __shared__ _Float16 Kbuf[2][2][64 * 64];
  __shared__ _Float16 Vbuf[2][2][64 * 64];
  const int bh = blockIdx.x;
  const int b = bh >> 4, h = bh & 15;
  const int q0 = blockIdx.y * 128;
  const int tid = threadIdx.x;
  const int wave = tid >> 6, lane = tid & 63, quad = lane >> 4, l16 = lane & 15;
  const int rx = l16 & 7;

  const _Float16* qbh = qb + (size_t)bh * S * HD;
  const _Float16* kbh = kb + (size_t)bh * S * HD;
  const _Float16* vbh = vt + (size_t)bh * S * HD;

  half8 aq[2];
#pragma unroll
  for (int ks = 0; ks < 2; ++ks)
    aq[ks] = *(const half8*)&qbh[(size_t)(q0 + wave * 16 + l16) * HD + ks * 32 + quad * 8];

  // staging: 512 thr x 16B = one 64x64 f16 tile per pass.
  // write addr: row rr, chunk c8 -> LDS chunk c8 ^ (rr&7)  (pitch 64).
  const int rr = tid >> 3, c8 = tid & 7;
  const int wofs = rr * 64 + ((c8 ^ (rr & 7)) * 8);
  // tile stride in both k_h and vT is 64*64 = 4096 elements.
  const _Float16* kp = kbh + (size_t)rr * HD + c8 * 8;
  const _Float16* vp = vbh + (size_t)rr * 64 + c8 * 8;

  half8 kr0, kr1, vr0, vr1;
  // pair 0 -> buf0
  kr0 = *(const half8*)kp; kr1 = *(const half8*)(kp + 4096);
  vr0 = *(const half8*)vp; vr1 = *(const half8*)(vp + 4096);
  *(half8*)&Kbuf[0][0][wofs] = kr0; *(half8*)&Kbuf[0][1][wofs] = kr1;
  *(half8*)&Vbuf[0][0][wofs] = vr0; *(half8*)&Vbuf[0][1][wofs] = vr1;
  kp += 8192; vp += 8192;
  // pair 1 -> regs
  kr0 = *(const half8*)kp; kr1 = *(const half8*)(kp + 4096);
  vr0 = *(const half8*)vp; vr1 = *(const half8*)(vp + 4096);
  __syncthreads();

  floatx4 o16[4] = {};
  float mrow = -INFINITY, lrow = 0.f;

  auto compute_pair = [&](const _Float16* K0, const _Float16* K1,
                          const _Float16* V0, const _Float16* V1) {
    // --- QK^T for both tiles (independent accumulators) ---
    floatx4 scA[4] = {}, scB[4] = {};
#pragma unroll
    for (int jj = 0; jj < 4; ++jj) {
#pragma unroll
      for (int ks = 0; ks < 2; ++ks) {
        const int co = (jj * 16 + l16) * 64 + (((ks * 4 + quad) ^ rx) * 8);
        half8 akA = *(const half8*)&K0[co];
        half8 akB = *(const half8*)&K1[co];
        scA[jj] = MFMA32(akA, aq[ks], scA[jj]);
        scB[jj] = MFMA32(akB, aq[ks], scB[jj]);
      }
    }

    // --- pack to f16 (2 independent streams) ---
    half2v phA[8], phB[8];
#pragma unroll
    for (int jj = 0; jj < 4; ++jj) {
      phA[jj * 2]     = pkrtz(scA[jj][0], scA[jj][1]);
      phA[jj * 2 + 1] = pkrtz(scA[jj][2], scA[jj][3]);
      phB[jj * 2]     = pkrtz(scB[jj][0], scB[jj][1]);
      phB[jj * 2 + 1] = pkrtz(scB[jj][2], scB[jj][3]);
    }
    // --- combined max: one update per PAIR of tiles ---
    half2v mA = hmax2(hmax2(hmax2(phA[0], phA[1]), hmax2(phA[2], phA[3])),
                      hmax2(hmax2(phA[4], phA[5]), hmax2(phA[6], phA[7])));
    half2v mB = hmax2(hmax2(hmax2(phB[0], phB[1]), hmax2(phB[2], phB[3])),
                      hmax2(hmax2(phB[4], phB[5]), hmax2(phB[6], phB[7])));
    half2v mx2 = hmax2(mA, mB);
    int mi = __builtin_bit_cast(int, mx2);
    mx2 = hmax2(mx2, __builtin_bit_cast(half2v, __shfl_xor(mi, 16)));
    mi = __builtin_bit_cast(int, mx2);
    mx2 = hmax2(mx2, __builtin_bit_cast(half2v, __shfl_xor(mi, 32)));
    const float mxf = fmaxf((float)mx2[0], (float)mx2[1]);
    // defer-max: P bounded by 2^4=16, safe in f16 / f32 accum.
    const bool up = mxf > mrow + 4.0f;
    const float mn = up ? mxf : mrow;
    const float alpha = up ? exp2f(mrow - mn) : 1.0f;
    mrow = mn;

    const _Float16 mnh = (_Float16)mn;
    half2v mn2; mn2[0] = mnh; mn2[1] = mnh;
    half2v peA[8], peB[8];
#pragma unroll
    for (int i = 0; i < 8; ++i) {
      peA[i] = __builtin_elementwise_exp2(phA[i] - mn2);
      peB[i] = __builtin_elementwise_exp2(phB[i] - mn2);
    }

    half2v one2; one2[0] = (_Float16)1.f; one2[1] = (_Float16)1.f;
    const fp16x2 one2p = __builtin_bit_cast(fp16x2, one2);
    float rsA = 0.f, rsB = 0.f;   // independent dot chains
#pragma unroll
    for (int i = 0; i < 8; ++i) {
      rsA = __builtin_amdgcn_fdot2(__builtin_bit_cast(fp16x2, peA[i]), one2p, rsA, false);
      rsB = __builtin_amdgcn_fdot2(__builtin_bit_cast(fp16x2, peB[i]), one2p, rsB, false);
    }
    float rs = rsA + rsB;
    rs += __shfl_xor(rs, 16);
    rs += __shfl_xor(rs, 32);
    lrow = lrow * alpha + rs;

    if (__ballot(up)) {          // one conditional rescale per 2 tiles
      float alr[4];
#pragma unroll
      for (int r = 0; r < 4; ++r) alr[r] = __shfl(alpha, quad * 4 + r);
#pragma unroll
      for (int jb = 0; jb < 4; ++jb)
#pragma unroll
        for (int r = 0; r < 4; ++r) o16[jb][r] *= alr[r];
    }

    half4v apA[4], apB[4];
#pragma unroll
    for (int jj = 0; jj < 4; ++jj) {
      apA[jj] = __builtin_shufflevector(peA[jj * 2], peA[jj * 2 + 1], 0, 1, 2, 3);
      apB[jj] = __builtin_shufflevector(peB[jj * 2], peB[jj * 2 + 1], 0, 1, 2, 3);
    }

    // --- O += P@V for both tiles, interleaved MFMAs ---
#pragma unroll
    for (int jb = 0; jb < 4; ++jb) {
      const int vrow = (jb * 16 + l16) * 64;
      half8 vA01 = *(const half8*)&V0[vrow + (((2 * quad)     ^ rx) * 8)];
      half8 vA23 = *(const half8*)&V0[vrow + (((2 * quad + 1) ^ rx) * 8)];
      half8 vB01 = *(const half8*)&V1[vrow + (((2 * quad)     ^ rx) * 8)];
      half8 vB23 = *(const half8*)&V1[vrow + (((2 * quad + 1) ^ rx) * 8)];
      half4v a0 = __builtin_shufflevector(vA01, vA01, 0, 1, 2, 3);
      half4v a1 = __builtin_shufflevector(vA01, vA01, 4, 5, 6, 7);
      half4v a2 = __builtin_shufflevector(vA23, vA23, 0, 1, 2, 3);
      half4v a3 = __builtin_shufflevector(vA23, vA23, 4, 5, 6, 7);
      half4v b0 = __builtin_shufflevector(vB01, vB01, 0, 1, 2, 3);
      half4v b1 = __builtin_shufflevector(vB01, vB01, 4, 5, 6, 7);
      half4v b2 = __builtin_shufflevector(vB23, vB23, 0, 1, 2, 3);
      half4v b3 = __builtin_shufflevector(vB23, vB23, 4, 5, 6, 7);
      o16[jb] = MFMA16(apA[0], a0, o16[jb]);
      o16[jb] = MFMA16(apB[0], b0, o16[jb]);
      o16[jb] = MFMA16(apA[1], a1, o16[jb]);
      o16[jb] = MFMA16(apB[1], b1, o16[jb]);
      o16[jb] = MFMA16(apA[2], a2, o16[jb]);
      o16[jb] = MFMA16(apB[2], b2, o16[jb]);
      o16[jb] = MFMA16(apA[3], a3, o16[jb]);
      o16[jb] = MFMA16(apB[3], b3, o16[jb]);
    }
  };

  int cur = 0;
  for (int p = 0; p < 16; ++p) {     // 16 pairs of 64-row K/V tiles
    if (p + 1 < 16) {
      *(half8*)&Kbuf[cur ^ 1][0][wofs] = kr0;
      *(half8*)&Kbuf[cur ^ 1][1][wofs] = kr1;
      *(half8*)&Vbuf[cur ^ 1][0][wofs] = vr0;
      *(half8*)&Vbuf[cur ^ 1][1][wofs] = vr1;
      if (p + 2 < 16) {
        kp += 8192; vp += 8192;
        kr0 = *(const half8*)kp; kr1 = *(const half8*)(kp + 4096);
        vr0 = *(const half8*)vp; vr1 = *(const half8*)(vp + 4096);
      }
    }
    compute_pair(Kbuf[cur][0], Kbuf[cur][1], Vbuf[cur][0], Vbuf[cur][1]);
    __syncthreads();
    cur ^= 1;
  }

  float linv[4];
#pragma unroll
  for (int r = 0; r < 4; ++r) linv[r] = 1.0f / __shfl(lrow, quad * 4 + r);
#pragma unroll
  for (int jb = 0; jb < 4; ++jb) {
#pragma unroll
    for (int r = 0; r < 4; ++r) {
      const int row = q0 + wave * 16 + quad * 4 + r;
      attnb[(size_t)(b * S + row) * INNER + h * HD + jb * 16 + l16] =
          (_Float16)(o16[jb][r] * linv[r]);
    }
  }
}

// ---------------------------------------------------------------------------
extern "C" void kernel_launch(void* const* d_in, const int* in_sizes, int n_in,
                              void* d_out, int out_size, void* d_ws, size_t ws_size,
                              hipStream_t stream) {
  const float* hs    = (const float*)d_in[0];
  const float* rot   = (const float*)d_in[1];
  const float* w_qkv = (const float*)d_in[2];
  const float* b_qkv = (const float*)d_in[3];
  const float* nqw   = (const float*)d_in[4];
  const float* nkw   = (const float*)d_in[5];
  const float* w_out = (const float*)d_in[6];
  const float* b_out = (const float*)d_in[7];
  const float* hks   = (const float*)d_in[8];
  const int*   octx  = (const int*)d_in[9];

  _Float16* hsb   = (_Float16*)d_ws;                 // 0-8 MiB (attnb aliases)
  _Float16* attnb = hsb;
  _Float16* wqkvT = hsb   + (size_t)NTOK * DIM;      // 8-14 MiB
  _Float16* woutT = wqkvT + (size_t)QKVN * DIM;      // 14-16 MiB
  _Float16* qkvh  = woutT + (size_t)DIM * INNER;     // 16-40 MiB
  _Float16* q_h   = qkvh  + (size_t)NTOK * QKVN;     // 40-48 MiB
  _Float16* k_h   = q_h   + (size_t)B * NH * S * HD; // 48-56 MiB
  _Float16* vT    = k_h   + (size_t)B * NH * S * HD; // 56-64 MiB

  prep_all<<<3072, 256, 0, stream>>>(hs, w_qkv, w_out, hsb, wqkvT, woutT);

  gemm_bt<true, _Float16><<<dim3(QKVN / 128, NTOK / 128), 256, 0, stream>>>(
      hsb, wqkvT, b_qkv, qkvh, QKVN, DIM);

  post_all<<<5120, 256, 0, stream>>>(qkvh, rot, nqw, nkw, hks, octx, q_h, k_h, vT);

  attn_mfma<<<dim3(B * NH, S / 128), 512, 0, stream>>>(q_h, k_h, vT, attnb);

  gemm_bt<false, float><<<dim3(DIM / 128, NTOK / 128), 256, 0, stream>>>(
      attnb, woutT, b_out, (float*)d_out, DIM, INNER);
}

// Round 4
// 215.220 us; speedup vs baseline: 1.3587x; 1.0017x over previous
//
#include <hip/hip_runtime.h>
#include <math.h>

typedef float    floatx4 __attribute__((ext_vector_type(4)));
typedef _Float16 half8   __attribute__((ext_vector_type(8)));
typedef _Float16 half4v  __attribute__((ext_vector_type(4)));
typedef _Float16 half2v  __attribute__((ext_vector_type(2)));
typedef __fp16   fp16x2  __attribute__((ext_vector_type(2)));

constexpr int B    = 2;
constexpr int S    = 2048;
constexpr int NH   = 16;
constexpr int HD   = 64;
constexpr int DIM  = 1024;
constexpr int INNER = 1024;
constexpr int QKVN = 3072;
constexpr int NTOK = 4096;
constexpr float EPS = 1e-5f;
constexpr float MAX_SCALE = 10.0f;
constexpr float SCALE_LOG2E = 0.125f * 1.4426950408889634f;

#define MFMA32(a, b, c) __builtin_amdgcn_mfma_f32_16x16x32_f16((a), (b), (c), 0, 0, 0)

__device__ __forceinline__ half2v pkrtz(float a, float b) {
  fp16x2 t = __builtin_amdgcn_cvt_pkrtz(a, b);
  return __builtin_bit_cast(half2v, t);
}
__device__ __forceinline__ half2v hmax2(half2v a, half2v b) {
  return __builtin_elementwise_max(a, b);
}

// Direct global->LDS DMA, 16 B per lane. LDS dest is wave-uniform base;
// HW writes at base + lane*16 (linear). Source address is per-lane, so
// swizzled LDS layouts are achieved by pre-swizzling the source (rule #21).
__device__ __forceinline__ void gl_lds16(const _Float16* g, _Float16* l) {
  __builtin_amdgcn_global_load_lds(
      (__attribute__((address_space(1))) void*)g,
      (__attribute__((address_space(3))) void*)l, 16, 0, 0);
}

// ---------------------------------------------------------------------------
// Fused prep: blockIdx [0,2048) fp32->fp16 convert of hs;
// [2048,2816) transpose w_qkv; [2816,3072) transpose w_out.
// ---------------------------------------------------------------------------
__device__ __forceinline__ void transpose_tile(const float* __restrict__ w,
                                               _Float16* __restrict__ wT,
                                               int K, int N, int k0, int n0,
                                               _Float16* T, int tid) {
#pragma unroll
  for (int i = 0; i < 4; ++i) {
    int id = tid + 256 * i;
    int r = id >> 4, c = id & 15;
    float4 v = *(const float4*)&w[(size_t)(k0 + r) * N + n0 + c * 4];
    half4v s; s[0] = (_Float16)v.x; s[1] = (_Float16)v.y;
    s[2] = (_Float16)v.z; s[3] = (_Float16)v.w;
    *(half4v*)&T[r * 72 + c * 4] = s;
  }
  __syncthreads();
#pragma unroll
  for (int i = 0; i < 2; ++i) {
    int id = tid + 256 * i;
    int n = id >> 3, cs = id & 7;
    half8 o;
#pragma unroll
    for (int jj = 0; jj < 8; ++jj) o[jj] = T[(cs * 8 + jj) * 72 + n];
    *(half8*)&wT[(size_t)(n0 + n) * K + k0 + cs * 8] = o;
  }
}

__global__ __launch_bounds__(256)
void prep_all(const float* __restrict__ hs, const float* __restrict__ w_qkv,
              const float* __restrict__ w_out, _Float16* __restrict__ hsb,
              _Float16* __restrict__ wqkvT, _Float16* __restrict__ woutT) {
  __shared__ _Float16 T[64 * 72];
  const int bx = blockIdx.x, tid = threadIdx.x;
  if (bx < 2048) {
    int id = bx * 256 + tid;
    const float4 a = ((const float4*)hs)[id * 2];
    const float4 b = ((const float4*)hs)[id * 2 + 1];
    half8 o;
    o[0] = (_Float16)a.x; o[1] = (_Float16)a.y; o[2] = (_Float16)a.z; o[3] = (_Float16)a.w;
    o[4] = (_Float16)b.x; o[5] = (_Float16)b.y; o[6] = (_Float16)b.z; o[7] = (_Float16)b.w;
    ((half8*)hsb)[id] = o;
  } else if (bx < 2816) {
    int id = bx - 2048;
    transpose_tile(w_qkv, wqkvT, DIM, QKVN, (id / 48) * 64, (id % 48) * 64, T, tid);
  } else {
    int id = bx - 2816;
    transpose_tile(w_out, woutT, INNER, DIM, (id / 16) * 64, (id % 16) * 64, T, tid);
  }
}

// ---------------------------------------------------------------------------
// fp16 MFMA GEMM, R4: BK=32 double-buffered (32 KB LDS -> 3 blocks/CU,
// exactly matching gemm1's 768-block grid; R3's 64 KB forced 2/CU with a
// half-empty second dispatch round). global_load_lds staging, 2-phase
// schedule. XOR swizzle c ^ ((row>>1)&3): with pitch 32h (row&1 rotates
// bank base by 16) fragment reads are 2-way per 16-lane window (free).
// Bijective XCD swizzle (nwg%8==0 for both call sites).
// ---------------------------------------------------------------------------
template<bool OUT_F16, typename OutT>
__global__ __launch_bounds__(256)
void gemm_bt(const _Float16* __restrict__ A, const _Float16* __restrict__ BT,
             const float* __restrict__ bias, OutT* __restrict__ C, int N, int K) {
  __shared__ _Float16 As[2][128 * 32];
  __shared__ _Float16 Bs[2][128 * 32];
  const int tid = threadIdx.x;
  const int wave = tid >> 6, lane = tid & 63, quad = lane >> 4, l16 = lane & 15;
  const int wm = wave >> 1, wn = wave & 1;

  // XCD-aware block swizzle (grid sizes are multiples of 8 -> bijective).
  const int gx = gridDim.x;
  int wg = blockIdx.y * gx + blockIdx.x;
  const int cpx = (gx * gridDim.y) >> 3;
  wg = (wg & 7) * cpx + (wg >> 3);
  const int m0 = (wg / gx) * 128, n0 = (wg % gx) * 128;

  // staging: instr i of wave w covers rows i*64 + w*16 + (lane>>2);
  // dest 16B-chunk = lane&3; source chunk = dest ^ ((srow>>1)&3).
  const int srow = lane >> 2;
  const int scol = ((lane & 3) ^ ((srow >> 1) & 3)) * 8;
  const _Float16* Ag = A  + (size_t)(m0 + wave * 16 + srow) * K + scol;
  const _Float16* Bg = BT + (size_t)(n0 + wave * 16 + srow) * K + scol;

  auto stage = [&](int k0, int buf) {
#pragma unroll
    for (int i = 0; i < 2; ++i) {
      gl_lds16(Ag + (size_t)(i * 64) * K + k0, &As[buf][(i * 64 + wave * 16) * 32]);
      gl_lds16(Bg + (size_t)(i * 64) * K + k0, &Bs[buf][(i * 64 + wave * 16) * 32]);
    }
  };

  floatx4 acc[4][4] = {};
  const int rsw = (l16 >> 1) & 3;

  stage(0, 0);
  __syncthreads();
  int cur = 0;
  for (int k0 = 0; k0 < K; k0 += 32) {
    if (k0 + 32 < K) stage(k0 + 32, cur ^ 1);   // async; flies under MFMAs
    half8 a[4], b[4];
#pragma unroll
    for (int i = 0; i < 4; ++i)
      a[i] = *(const half8*)&As[cur][(wm * 64 + i * 16 + l16) * 32 + ((quad ^ rsw) * 8)];
#pragma unroll
    for (int j = 0; j < 4; ++j)
      b[j] = *(const half8*)&Bs[cur][(wn * 64 + j * 16 + l16) * 32 + ((quad ^ rsw) * 8)];
#pragma unroll
    for (int i = 0; i < 4; ++i)
#pragma unroll
      for (int j = 0; j < 4; ++j)
        acc[i][j] = MFMA32(a[i], b[j], acc[i][j]);
    __syncthreads();   // drains vmcnt(0): next buffer staged + reads done
    cur ^= 1;
  }

  const int rb = m0 + wm * 64 + quad * 4;
  const int cb = n0 + wn * 64 + l16;
#pragma unroll
  for (int j = 0; j < 4; ++j) {
    const float bj = bias[cb + j * 16];
#pragma unroll
    for (int i = 0; i < 4; ++i) {
#pragma unroll
      for (int r = 0; r < 4; ++r) {
        float v = acc[i][j][r] + bj;
        size_t idx = (size_t)(rb + i * 16 + r) * N + cb + j * 16;
        if constexpr (OUT_F16) C[idx] = (_Float16)v; else C[idx] = v;
      }
    }
  }
}

// ---------------------------------------------------------------------------
// Fused post: blockIdx [0,4096) = per-token RMSNorm+rotary+hist-scale;
// [4096,5120) = V transpose/swizzle tiles (fragment order for PV MFMAs).
// ---------------------------------------------------------------------------
__global__ __launch_bounds__(256)
void post_all(const _Float16* __restrict__ qkvh, const float* __restrict__ rot,
              const float* __restrict__ nqw, const float* __restrict__ nkw,
              const float* __restrict__ hks, const int* __restrict__ octx,
              _Float16* __restrict__ qo_, _Float16* __restrict__ ko_,
              _Float16* __restrict__ vt) {
  __shared__ __align__(16) char arena[64 * 72 * 2];
  const int tid = threadIdx.x;
  if (blockIdx.x < 4096) {
    float* red = (float*)arena;
    const int token = blockIdx.x;
    const int b = token >> 11, spos = token & (S - 1);
    const _Float16* qrow = qkvh + (size_t)token * QKVN;
    const _Float16* krow = qrow + INNER;
    const float* r = rot + (size_t)token * (2 * HD);

    const int e0 = tid * 4;
    half4v qs = *(const half4v*)(qrow + e0);
    half4v ks = *(const half4v*)(krow + e0);
    float q4[4], k4[4];
#pragma unroll
    for (int i = 0; i < 4; ++i) { q4[i] = (float)qs[i]; k4[i] = (float)ks[i]; }

    float sq = 0.f, sk = 0.f;
#pragma unroll
    for (int i = 0; i < 4; ++i) { sq += q4[i] * q4[i]; sk += k4[i] * k4[i]; }
#pragma unroll
    for (int msk = 1; msk < 64; msk <<= 1) {
      sq += __shfl_xor(sq, msk);
      sk += __shfl_xor(sk, msk);
    }
    const int wv = tid >> 6;
    if ((tid & 63) == 0) { red[wv] = sq; red[4 + wv] = sk; }
    __syncthreads();
    sq = red[0] + red[1] + red[2] + red[3];
    sk = red[4] + red[5] + red[6] + red[7];

    const float qinv = 1.0f / sqrtf(sq * (1.0f / INNER) + EPS);
    const float kinv = 1.0f / sqrtf(sk * (1.0f / INNER) + EPS);

#pragma unroll
    for (int i = 0; i < 4; ++i) {
      q4[i] = q4[i] * qinv * nqw[e0 + i];
      k4[i] = k4[i] * kinv * nkw[e0 + i];
    }

    const int h = e0 >> 6, d0 = e0 & (HD - 1);
    const float c0 = r[d0],     s0 = r[HD + d0 + 1];
    const float c1 = r[d0 + 2], s1 = r[HD + d0 + 3];

    float qo[4], ko[4];
    qo[0] = q4[0] * c0 - q4[1] * s0;
    qo[1] = q4[0] * s0 + q4[1] * c0;
    qo[2] = q4[2] * c1 - q4[3] * s1;
    qo[3] = q4[2] * s1 + q4[3] * c1;
    ko[0] = k4[0] * c0 - k4[1] * s0;
    ko[1] = k4[0] * s0 + k4[1] * c0;
    ko[2] = k4[2] * c1 - k4[3] * s1;
    ko[3] = k4[2] * s1 + k4[3] * c1;

    const int hist = S - octx[0];
    if (hist > 0 && spos < hist) {
      const float sig = 1.0f / (1.0f + expf(-hks[h]));
      const float sc = 1.0f + sig * (MAX_SCALE - 1.0f);
#pragma unroll
      for (int i = 0; i < 4; ++i) ko[i] *= sc;
    }

    half4v qo4, ko4;
#pragma unroll
    for (int i = 0; i < 4; ++i) {
      qo4[i] = (_Float16)(qo[i] * SCALE_LOG2E);
      ko4[i] = (_Float16)ko[i];
    }
    const size_t obase = ((size_t)(b * NH + h) * S + spos) * HD + d0;
    *(half4v*)(qo_ + obase) = qo4;
    *(half4v*)(ko_ + obase) = ko4;
  } else {
    _Float16* T = (_Float16*)arena;
    const int id = blockIdx.x - 4096;
    const int bh = id & 31, kt = id >> 5;
    const int b = bh >> 4, h = bh & 15;
    const int s0 = kt * 64;
#pragma unroll
    for (int i = 0; i < 2; ++i) {
      int id2 = tid + 256 * i;
      int s = id2 >> 3, c = id2 & 7;
      *(half8*)&T[s * 72 + c * 8] =
          *(const half8*)&qkvh[(size_t)(b * S + s0 + s) * QKVN + 2 * INNER + h * HD + c * 8];
    }
    __syncthreads();
    _Float16* orow = vt + ((size_t)bh * 32 + kt) * 64 * 64;
#pragma unroll
    for (int i = 0; i < 4; ++i) {
      int id2 = tid + 256 * i;
      int d = id2 >> 4, g = id2 & 15;
      int quad = g >> 2, jj = g & 3;
      half4v o;
#pragma unroll
      for (int k = 0; k < 4; ++k) o[k] = T[(jj * 16 + quad * 4 + k) * 72 + d];
      *(half4v*)&orow[d * 64 + g * 4] = o;
    }
  }
}

// ---------------------------------------------------------------------------
// MFMA flash attention, R4: R3 structure (8 waves, 16 Q-rows/wave, 2 K-tiles
// per barrier with shared max-update) with two upgrades:
//  1. PV via 16x16x32 MFMA: A = [ap[2t] | ap[2t+1]] defines k(q,e) =
//     16(e>>2)+4q+(e&3); vT position p = 16q+8t+e supplies V[32t+k(q,e)][d]
//     as ONE contiguous 16B read (same addresses as before, half the MFMAs,
//     double the per-instruction FLOPs). No cross-lane shuffles needed.
//  2. Staging via global_load_lds DMA: K/V tiles are contiguous 8KB blocks;
//     source pre-swizzled per rule #21 so LDS[row][c] = G[row][c^(row&7)].
//     Removes the global->VGPR->ds_write round trip entirely.
// ---------------------------------------------------------------------------
__global__ __launch_bounds__(512, 4)
void attn_mfma(const _Float16* __restrict__ qb, const _Float16* __restrict__ kb,
               const _Float16* __restrict__ vt, _Float16* __restrict__ attnb) {
  __shared__ _Float16 Kbuf[2][2][64 * 64];
  __shared__ _Float16 Vbuf[2][2][64 * 64];
  const int bh = blockIdx.x;
  const int b = bh >> 4, h = bh & 15;
  const int q0 = blockIdx.y * 128;
  const int tid = threadIdx.x;
  const int wave = tid >> 6, lane = tid & 63, quad = lane >> 4, l16 = lane & 15;
  const int rx = l16 & 7;

  const _Float16* qbh = qb + (size_t)bh * S * HD;
  const _Float16* kbh = kb + (size_t)bh * S * HD;
  const _Float16* vbh = vt + (size_t)bh * S * HD;

  half8 aq[2];
#pragma unroll
  for (int ks = 0; ks < 2; ++ks)
    aq[ks] = *(const half8*)&qbh[(size_t)(q0 + wave * 16 + l16) * HD + ks * 32 + quad * 8];

  // DMA staging: per wave one gl_lds16 covers 8 rows x 64 cols (1 KB).
  // dest halves = wave*512 + lane*8 -> row = wave*8 + (lane>>3), chunk = lane&7.
  // source pre-swizzled: G-chunk = (lane&7) ^ (row&7).
  const int srow = wave * 8 + (lane >> 3);
  const int soff = srow * 64 + (((lane & 7) ^ (srow & 7)) * 8);

  auto stage = [&](int p, int buf) {
    const _Float16* kt = kbh + (size_t)p * 8192;
    const _Float16* vp = vbh + (size_t)p * 8192;
    gl_lds16(kt + soff,        &Kbuf[buf][0][wave * 512]);
    gl_lds16(kt + 4096 + soff, &Kbuf[buf][1][wave * 512]);
    gl_lds16(vp + soff,        &Vbuf[buf][0][wave * 512]);
    gl_lds16(vp + 4096 + soff, &Vbuf[buf][1][wave * 512]);
  };

  stage(0, 0);
  __syncthreads();   // drains vmcnt(0): pair 0 resident

  floatx4 o16[4] = {};
  float mrow = -INFINITY, lrow = 0.f;

  auto compute_pair = [&](const _Float16* K0, const _Float16* K1,
                          const _Float16* V0, const _Float16* V1) {
    // --- QK^T for both tiles (independent accumulators) ---
    floatx4 scA[4] = {}, scB[4] = {};
#pragma unroll
    for (int jj = 0; jj < 4; ++jj) {
#pragma unroll
      for (int ks = 0; ks < 2; ++ks) {
        const int co = (jj * 16 + l16) * 64 + (((ks * 4 + quad) ^ rx) * 8);
        half8 akA = *(const half8*)&K0[co];
        half8 akB = *(const half8*)&K1[co];
        scA[jj] = MFMA32(akA, aq[ks], scA[jj]);
        scB[jj] = MFMA32(akB, aq[ks], scB[jj]);
      }
    }

    // --- pack to f16 (2 independent streams) ---
    half2v phA[8], phB[8];
#pragma unroll
    for (int jj = 0; jj < 4; ++jj) {
      phA[jj * 2]     = pkrtz(scA[jj][0], scA[jj][1]);
      phA[jj * 2 + 1] = pkrtz(scA[jj][2], scA[jj][3]);
      phB[jj * 2]     = pkrtz(scB[jj][0], scB[jj][1]);
      phB[jj * 2 + 1] = pkrtz(scB[jj][2], scB[jj][3]);
    }
    // --- combined max: one update per PAIR of tiles ---
    half2v mA = hmax2(hmax2(hmax2(phA[0], phA[1]), hmax2(phA[2], phA[3])),
                      hmax2(hmax2(phA[4], phA[5]), hmax2(phA[6], phA[7])));
    half2v mB = hmax2(hmax2(hmax2(phB[0], phB[1]), hmax2(phB[2], phB[3])),
                      hmax2(hmax2(phB[4], phB[5]), hmax2(phB[6], phB[7])));
    half2v mx2 = hmax2(mA, mB);
    int mi = __builtin_bit_cast(int, mx2);
    mx2 = hmax2(mx2, __builtin_bit_cast(half2v, __shfl_xor(mi, 16)));
    mi = __builtin_bit_cast(int, mx2);
    mx2 = hmax2(mx2, __builtin_bit_cast(half2v, __shfl_xor(mi, 32)));
    const float mxf = fmaxf((float)mx2[0], (float)mx2[1]);
    // defer-max: P bounded by 2^4=16, safe in f16 / f32 accum.
    const bool up = mxf > mrow + 4.0f;
    const float mn = up ? mxf : mrow;
    const float alpha = up ? exp2f(mrow - mn) : 1.0f;
    mrow = mn;

    const _Float16 mnh = (_Float16)mn;
    half2v mn2; mn2[0] = mnh; mn2[1] = mnh;
    half2v peA[8], peB[8];
#pragma unroll
    for (int i = 0; i < 8; ++i) {
      peA[i] = __builtin_elementwise_exp2(phA[i] - mn2);
      peB[i] = __builtin_elementwise_exp2(phB[i] - mn2);
    }

    half2v one2; one2[0] = (_Float16)1.f; one2[1] = (_Float16)1.f;
    const fp16x2 one2p = __builtin_bit_cast(fp16x2, one2);
    float rsA = 0.f, rsB = 0.f;   // independent dot chains
#pragma unroll
    for (int i = 0; i < 8; ++i) {
      rsA = __builtin_amdgcn_fdot2(__builtin_bit_cast(fp16x2, peA[i]), one2p, rsA, false);
      rsB = __builtin_amdgcn_fdot2(__builtin_bit_cast(fp16x2, peB[i]), one2p, rsB, false);
    }
    float rs = rsA + rsB;
    rs += __shfl_xor(rs, 16);
    rs += __shfl_xor(rs, 32);
    lrow = lrow * alpha + rs;

    if (__ballot(up)) {          // one conditional rescale per 2 tiles
      float alr[4];
#pragma unroll
      for (int r = 0; r < 4; ++r) alr[r] = __shfl(alpha, quad * 4 + r);
#pragma unroll
      for (int jb = 0; jb < 4; ++jb)
#pragma unroll
        for (int r = 0; r < 4; ++r) o16[jb][r] *= alr[r];
    }

    // --- K=32 A-frags for PV: pA[t] = [cols of block 2t | block 2t+1] ---
    half8 pA[2], pB[2];
#pragma unroll
    for (int t = 0; t < 2; ++t) {
      half4v loA = __builtin_shufflevector(peA[4 * t],     peA[4 * t + 1], 0, 1, 2, 3);
      half4v hiA = __builtin_shufflevector(peA[4 * t + 2], peA[4 * t + 3], 0, 1, 2, 3);
      pA[t] = __builtin_shufflevector(loA, hiA, 0, 1, 2, 3, 4, 5, 6, 7);
      half4v loB = __builtin_shufflevector(peB[4 * t],     peB[4 * t + 1], 0, 1, 2, 3);
      half4v hiB = __builtin_shufflevector(peB[4 * t + 2], peB[4 * t + 3], 0, 1, 2, 3);
      pB[t] = __builtin_shufflevector(loB, hiB, 0, 1, 2, 3, 4, 5, 6, 7);
    }

    // --- O += P@V : 16x16x32 MFMAs, one 16B V read each ---
#pragma unroll
    for (int jb = 0; jb < 4; ++jb) {
      const int vrow = (jb * 16 + l16) * 64;
#pragma unroll
      for (int t = 0; t < 2; ++t) {
        half8 vA = *(const half8*)&V0[vrow + (((2 * quad + t) ^ rx) * 8)];
        half8 vB = *(const half8*)&V1[vrow + (((2 * quad + t) ^ rx) * 8)];
        o16[jb] = MFMA32(pA[t], vA, o16[jb]);
        o16[jb] = MFMA32(pB[t], vB, o16[jb]);
      }
    }
  };

  int cur = 0;
  for (int p = 0; p < 16; ++p) {     // 16 pairs of 64-row K/V tiles
    if (p + 1 < 16) stage(p + 1, cur ^ 1);   // DMA; flies under compute
    compute_pair(Kbuf[cur][0], Kbuf[cur][1], Vbuf[cur][0], Vbuf[cur][1]);
    __syncthreads();                         // drains vmcnt: next pair ready
    cur ^= 1;
  }

  float linv[4];
#pragma unroll
  for (int r = 0; r < 4; ++r) linv[r] = 1.0f / __shfl(lrow, quad * 4 + r);
#pragma unroll
  for (int jb = 0; jb < 4; ++jb) {
#pragma unroll
    for (int r = 0; r < 4; ++r) {
      const int row = q0 + wave * 16 + quad * 4 + r;
      attnb[(size_t)(b * S + row) * INNER + h * HD + jb * 16 + l16] =
          (_Float16)(o16[jb][r] * linv[r]);
    }
  }
}

// ---------------------------------------------------------------------------
extern "C" void kernel_launch(void* const* d_in, const int* in_sizes, int n_in,
                              void* d_out, int out_size, void* d_ws, size_t ws_size,
                              hipStream_t stream) {
  const float* hs    = (const float*)d_in[0];
  const float* rot   = (const float*)d_in[1];
  const float* w_qkv = (const float*)d_in[2];
  const float* b_qkv = (const float*)d_in[3];
  const float* nqw   = (const float*)d_in[4];
  const float* nkw   = (const float*)d_in[5];
  const float* w_out = (const float*)d_in[6];
  const float* b_out = (const float*)d_in[7];
  const float* hks   = (const float*)d_in[8];
  const int*   octx  = (const int*)d_in[9];

  _Float16* hsb   = (_Float16*)d_ws;                 // 0-8 MiB (attnb aliases)
  _Float16* attnb = hsb;
  _Float16* wqkvT = hsb   + (size_t)NTOK * DIM;      // 8-14 MiB
  _Float16* woutT = wqkvT + (size_t)QKVN * DIM;      // 14-16 MiB
  _Float16* qkvh  = woutT + (size_t)DIM * INNER;     // 16-40 MiB
  _Float16* q_h   = qkvh  + (size_t)NTOK * QKVN;     // 40-48 MiB
  _Float16* k_h   = q_h   + (size_t)B * NH * S * HD; // 48-56 MiB
  _Float16* vT    = k_h   + (size_t)B * NH * S * HD; // 56-64 MiB

  prep_all<<<3072, 256, 0, stream>>>(hs, w_qkv, w_out, hsb, wqkvT, woutT);

  gemm_bt<true, _Float16><<<dim3(QKVN / 128, NTOK / 128), 256, 0, stream>>>(
      hsb, wqkvT, b_qkv, qkvh, QKVN, DIM);

  post_all<<<5120, 256, 0, stream>>>(qkvh, rot, nqw, nkw, hks, octx, q_h, k_h, vT);

  attn_mfma<<<dim3(B * NH, S / 128), 512, 0, stream>>>(q_h, k_h, vT, attnb);

  gemm_bt<false, float><<<dim3(DIM / 128, NTOK / 128), 256, 0, stream>>>(
      attnb, woutT, b_out, (float*)d_out, DIM, INNER);
}

// Round 5
// 203.885 us; speedup vs baseline: 1.4342x; 1.0556x over previous
//
#include <hip/hip_runtime.h>
#include <math.h>

typedef float    floatx4 __attribute__((ext_vector_type(4)));
typedef _Float16 half8   __attribute__((ext_vector_type(8)));
typedef _Float16 half4v  __attribute__((ext_vector_type(4)));
typedef _Float16 half2v  __attribute__((ext_vector_type(2)));
typedef __fp16   fp16x2  __attribute__((ext_vector_type(2)));

constexpr int B    = 2;
constexpr int S    = 2048;
constexpr int NH   = 16;
constexpr int HD   = 64;
constexpr int DIM  = 1024;
constexpr int INNER = 1024;
constexpr int QKVN = 3072;
constexpr int NTOK = 4096;
constexpr float EPS = 1e-5f;
constexpr float MAX_SCALE = 10.0f;
constexpr float SCALE_LOG2E = 0.125f * 1.4426950408889634f;

#define MFMA32(a, b, c) __builtin_amdgcn_mfma_f32_16x16x32_f16((a), (b), (c), 0, 0, 0)

__device__ __forceinline__ half2v pkrtz(float a, float b) {
  fp16x2 t = __builtin_amdgcn_cvt_pkrtz(a, b);
  return __builtin_bit_cast(half2v, t);
}
__device__ __forceinline__ half2v hmax2(half2v a, half2v b) {
  return __builtin_elementwise_max(a, b);
}

// Direct global->LDS DMA, 16 B per lane. LDS dest is wave-uniform base;
// HW writes at base + lane*16 (linear). Source address is per-lane, so
// swizzled LDS layouts are achieved by pre-swizzling the source (rule #21).
__device__ __forceinline__ void gl_lds16(const _Float16* g, _Float16* l) {
  __builtin_amdgcn_global_load_lds(
      (__attribute__((address_space(1))) void*)g,
      (__attribute__((address_space(3))) void*)l, 16, 0, 0);
}

// ---------------------------------------------------------------------------
// Fused prep: blockIdx [0,2048) fp32->fp16 convert of hs;
// [2048,2816) transpose w_qkv; [2816,3072) transpose w_out.
// ---------------------------------------------------------------------------
__device__ __forceinline__ void transpose_tile(const float* __restrict__ w,
                                               _Float16* __restrict__ wT,
                                               int K, int N, int k0, int n0,
                                               _Float16* T, int tid) {
#pragma unroll
  for (int i = 0; i < 4; ++i) {
    int id = tid + 256 * i;
    int r = id >> 4, c = id & 15;
    float4 v = *(const float4*)&w[(size_t)(k0 + r) * N + n0 + c * 4];
    half4v s; s[0] = (_Float16)v.x; s[1] = (_Float16)v.y;
    s[2] = (_Float16)v.z; s[3] = (_Float16)v.w;
    *(half4v*)&T[r * 72 + c * 4] = s;
  }
  __syncthreads();
#pragma unroll
  for (int i = 0; i < 2; ++i) {
    int id = tid + 256 * i;
    int n = id >> 3, cs = id & 7;
    half8 o;
#pragma unroll
    for (int jj = 0; jj < 8; ++jj) o[jj] = T[(cs * 8 + jj) * 72 + n];
    *(half8*)&wT[(size_t)(n0 + n) * K + k0 + cs * 8] = o;
  }
}

__global__ __launch_bounds__(256)
void prep_all(const float* __restrict__ hs, const float* __restrict__ w_qkv,
              const float* __restrict__ w_out, _Float16* __restrict__ hsb,
              _Float16* __restrict__ wqkvT, _Float16* __restrict__ woutT) {
  __shared__ _Float16 T[64 * 72];
  const int bx = blockIdx.x, tid = threadIdx.x;
  if (bx < 2048) {
    int id = bx * 256 + tid;
    const float4 a = ((const float4*)hs)[id * 2];
    const float4 b = ((const float4*)hs)[id * 2 + 1];
    half8 o;
    o[0] = (_Float16)a.x; o[1] = (_Float16)a.y; o[2] = (_Float16)a.z; o[3] = (_Float16)a.w;
    o[4] = (_Float16)b.x; o[5] = (_Float16)b.y; o[6] = (_Float16)b.z; o[7] = (_Float16)b.w;
    ((half8*)hsb)[id] = o;
  } else if (bx < 2816) {
    int id = bx - 2048;
    transpose_tile(w_qkv, wqkvT, DIM, QKVN, (id / 48) * 64, (id % 48) * 64, T, tid);
  } else {
    int id = bx - 2816;
    transpose_tile(w_out, woutT, INNER, DIM, (id / 16) * 64, (id % 16) * 64, T, tid);
  }
}

// ---------------------------------------------------------------------------
// fp16 MFMA GEMM with register-prefetch staging — REVERTED to the R0 version.
// Session evidence: non-attn time R0 (this GEMM) = 152 us; all
// global_load_lds variants (R1-R4) = 157-162 us. This is the measured best.
// ---------------------------------------------------------------------------
template<bool OUT_F16, typename OutT>
__global__ __launch_bounds__(256)
void gemm_bt(const _Float16* __restrict__ A, const _Float16* __restrict__ BT,
             const float* __restrict__ bias, OutT* __restrict__ C, int N, int K) {
  __shared__ _Float16 As[128 * 56];
  __shared__ _Float16 Bs[128 * 56];
  const int tid = threadIdx.x;
  const int wave = tid >> 6, lane = tid & 63, quad = lane >> 4, l16 = lane & 15;
  const int wm = wave >> 1, wn = wave & 1;
  const int m0 = blockIdx.y * 128, n0 = blockIdx.x * 128;

  const int id0 = tid, id1 = tid + 256;
  const int m_0 = id0 >> 2, c_0 = (id0 & 3) * 8;
  const int m_1 = id1 >> 2, c_1 = (id1 & 3) * 8;
  const _Float16* Ap0 = A + (size_t)(m0 + m_0) * K + c_0;
  const _Float16* Ap1 = A + (size_t)(m0 + m_1) * K + c_1;
  const _Float16* Bp0 = BT + (size_t)(n0 + m_0) * K + c_0;
  const _Float16* Bp1 = BT + (size_t)(n0 + m_1) * K + c_1;

  half8 ar0 = *(const half8*)Ap0, ar1 = *(const half8*)Ap1;
  half8 br0 = *(const half8*)Bp0, br1 = *(const half8*)Bp1;

  floatx4 acc[4][4] = {};

  for (int k0 = 0; k0 < K; k0 += 32) {
    __syncthreads();
    *(half8*)&As[m_0 * 56 + c_0] = ar0;
    *(half8*)&As[m_1 * 56 + c_1] = ar1;
    *(half8*)&Bs[m_0 * 56 + c_0] = br0;
    *(half8*)&Bs[m_1 * 56 + c_1] = br1;
    if (k0 + 32 < K) {
      ar0 = *(const half8*)(Ap0 + k0 + 32);
      ar1 = *(const half8*)(Ap1 + k0 + 32);
      br0 = *(const half8*)(Bp0 + k0 + 32);
      br1 = *(const half8*)(Bp1 + k0 + 32);
    }
    __syncthreads();
    half8 a[4], b[4];
#pragma unroll
    for (int i = 0; i < 4; ++i)
      a[i] = *(const half8*)&As[(wm * 64 + i * 16 + l16) * 56 + quad * 8];
#pragma unroll
    for (int j = 0; j < 4; ++j)
      b[j] = *(const half8*)&Bs[(wn * 64 + j * 16 + l16) * 56 + quad * 8];
#pragma unroll
    for (int i = 0; i < 4; ++i)
#pragma unroll
      for (int j = 0; j < 4; ++j)
        acc[i][j] = MFMA32(a[i], b[j], acc[i][j]);
  }

  const int rb = m0 + wm * 64 + quad * 4;
  const int cb = n0 + wn * 64 + l16;
#pragma unroll
  for (int j = 0; j < 4; ++j) {
    const float bj = bias[cb + j * 16];
#pragma unroll
    for (int i = 0; i < 4; ++i) {
#pragma unroll
      for (int r = 0; r < 4; ++r) {
        float v = acc[i][j][r] + bj;
        size_t idx = (size_t)(rb + i * 16 + r) * N + cb + j * 16;
        if constexpr (OUT_F16) C[idx] = (_Float16)v; else C[idx] = v;
      }
    }
  }
}

// ---------------------------------------------------------------------------
// Fused post: blockIdx [0,4096) = per-token RMSNorm+rotary+hist-scale;
// [4096,5120) = V transpose/swizzle tiles (fragment order for PV MFMAs).
// ---------------------------------------------------------------------------
__global__ __launch_bounds__(256)
void post_all(const _Float16* __restrict__ qkvh, const float* __restrict__ rot,
              const float* __restrict__ nqw, const float* __restrict__ nkw,
              const float* __restrict__ hks, const int* __restrict__ octx,
              _Float16* __restrict__ qo_, _Float16* __restrict__ ko_,
              _Float16* __restrict__ vt) {
  __shared__ __align__(16) char arena[64 * 72 * 2];
  const int tid = threadIdx.x;
  if (blockIdx.x < 4096) {
    float* red = (float*)arena;
    const int token = blockIdx.x;
    const int b = token >> 11, spos = token & (S - 1);
    const _Float16* qrow = qkvh + (size_t)token * QKVN;
    const _Float16* krow = qrow + INNER;
    const float* r = rot + (size_t)token * (2 * HD);

    const int e0 = tid * 4;
    half4v qs = *(const half4v*)(qrow + e0);
    half4v ks = *(const half4v*)(krow + e0);
    float q4[4], k4[4];
#pragma unroll
    for (int i = 0; i < 4; ++i) { q4[i] = (float)qs[i]; k4[i] = (float)ks[i]; }

    float sq = 0.f, sk = 0.f;
#pragma unroll
    for (int i = 0; i < 4; ++i) { sq += q4[i] * q4[i]; sk += k4[i] * k4[i]; }
#pragma unroll
    for (int msk = 1; msk < 64; msk <<= 1) {
      sq += __shfl_xor(sq, msk);
      sk += __shfl_xor(sk, msk);
    }
    const int wv = tid >> 6;
    if ((tid & 63) == 0) { red[wv] = sq; red[4 + wv] = sk; }
    __syncthreads();
    sq = red[0] + red[1] + red[2] + red[3];
    sk = red[4] + red[5] + red[6] + red[7];

    const float qinv = 1.0f / sqrtf(sq * (1.0f / INNER) + EPS);
    const float kinv = 1.0f / sqrtf(sk * (1.0f / INNER) + EPS);

#pragma unroll
    for (int i = 0; i < 4; ++i) {
      q4[i] = q4[i] * qinv * nqw[e0 + i];
      k4[i] = k4[i] * kinv * nkw[e0 + i];
    }

    const int h = e0 >> 6, d0 = e0 & (HD - 1);
    const float c0 = r[d0],     s0 = r[HD + d0 + 1];
    const float c1 = r[d0 + 2], s1 = r[HD + d0 + 3];

    float qo[4], ko[4];
    qo[0] = q4[0] * c0 - q4[1] * s0;
    qo[1] = q4[0] * s0 + q4[1] * c0;
    qo[2] = q4[2] * c1 - q4[3] * s1;
    qo[3] = q4[2] * s1 + q4[3] * c1;
    ko[0] = k4[0] * c0 - k4[1] * s0;
    ko[1] = k4[0] * s0 + k4[1] * c0;
    ko[2] = k4[2] * c1 - k4[3] * s1;
    ko[3] = k4[2] * s1 + k4[3] * c1;

    const int hist = S - octx[0];
    if (hist > 0 && spos < hist) {
      const float sig = 1.0f / (1.0f + expf(-hks[h]));
      const float sc = 1.0f + sig * (MAX_SCALE - 1.0f);
#pragma unroll
      for (int i = 0; i < 4; ++i) ko[i] *= sc;
    }

    half4v qo4, ko4;
#pragma unroll
    for (int i = 0; i < 4; ++i) {
      qo4[i] = (_Float16)(qo[i] * SCALE_LOG2E);
      ko4[i] = (_Float16)ko[i];
    }
    const size_t obase = ((size_t)(b * NH + h) * S + spos) * HD + d0;
    *(half4v*)(qo_ + obase) = qo4;
    *(half4v*)(ko_ + obase) = ko4;
  } else {
    _Float16* T = (_Float16*)arena;
    const int id = blockIdx.x - 4096;
    const int bh = id & 31, kt = id >> 5;
    const int b = bh >> 4, h = bh & 15;
    const int s0 = kt * 64;
#pragma unroll
    for (int i = 0; i < 2; ++i) {
      int id2 = tid + 256 * i;
      int s = id2 >> 3, c = id2 & 7;
      *(half8*)&T[s * 72 + c * 8] =
          *(const half8*)&qkvh[(size_t)(b * S + s0 + s) * QKVN + 2 * INNER + h * HD + c * 8];
    }
    __syncthreads();
    _Float16* orow = vt + ((size_t)bh * 32 + kt) * 64 * 64;
#pragma unroll
    for (int i = 0; i < 4; ++i) {
      int id2 = tid + 256 * i;
      int d = id2 >> 4, g = id2 & 15;
      int quad = g >> 2, jj = g & 3;
      half4v o;
#pragma unroll
      for (int k = 0; k < 4; ++k) o[k] = T[(jj * 16 + quad * 4 + k) * 72 + d];
      *(half4v*)&orow[d * 64 + g * 4] = o;
    }
  }
}

// ---------------------------------------------------------------------------
// MFMA flash attention, R5: R4 structure (8 waves, 16 Q-rows/wave, 2 K-tiles
// per barrier with shared max-update, DMA staging, PV via 16x16x32) plus the
// ones-MFMA row-sum: l is accumulated by MFMA32(p, ones, lacc) on the 25%-
// busy MFMA pipe instead of 16 fdot2 + 4 cross-lane shuffles on the 46%-busy
// VALU pipe. lacc lands in the SAME row layout as o16 -> linv needs no
// shuffles at all.
// ---------------------------------------------------------------------------
__global__ __launch_bounds__(512, 4)
void attn_mfma(const _Float16* __restrict__ qb, const _Float16* __restrict__ kb,
               const _Float16* __restrict__ vt, _Float16* __restrict__ attnb) {
  __shared__ _Float16 Kbuf[2][2][64 * 64];
  __shared__ _Float16 Vbuf[2][2][64 * 64];
  const int bh = blockIdx.x;
  const int b = bh >> 4, h = bh & 15;
  const int q0 = blockIdx.y * 128;
  const int tid = threadIdx.x;
  const int wave = tid >> 6, lane = tid & 63, quad = lane >> 4, l16 = lane & 15;
  const int rx = l16 & 7;

  const _Float16* qbh = qb + (size_t)bh * S * HD;
  const _Float16* kbh = kb + (size_t)bh * S * HD;
  const _Float16* vbh = vt + (size_t)bh * S * HD;

  half8 aq[2];
#pragma unroll
  for (int ks = 0; ks < 2; ++ks)
    aq[ks] = *(const half8*)&qbh[(size_t)(q0 + wave * 16 + l16) * HD + ks * 32 + quad * 8];

  // DMA staging: per wave one gl_lds16 covers 8 rows x 64 cols (1 KB).
  // dest halves = wave*512 + lane*8 -> row = wave*8 + (lane>>3), chunk = lane&7.
  // source pre-swizzled: G-chunk = (lane&7) ^ (row&7).
  const int srow = wave * 8 + (lane >> 3);
  const int soff = srow * 64 + (((lane & 7) ^ (srow & 7)) * 8);

  auto stage = [&](int p, int buf) {
    const _Float16* kt = kbh + (size_t)p * 8192;
    const _Float16* vp = vbh + (size_t)p * 8192;
    gl_lds16(kt + soff,        &Kbuf[buf][0][wave * 512]);
    gl_lds16(kt + 4096 + soff, &Kbuf[buf][1][wave * 512]);
    gl_lds16(vp + soff,        &Vbuf[buf][0][wave * 512]);
    gl_lds16(vp + 4096 + soff, &Vbuf[buf][1][wave * 512]);
  };

  stage(0, 0);
  __syncthreads();   // drains vmcnt(0): pair 0 resident

  floatx4 o16[4] = {};
  floatx4 lacc = {};                      // row-sums, same layout as o16 rows
  float mrow = -INFINITY;

  half8 ones8;
#pragma unroll
  for (int i = 0; i < 8; ++i) ones8[i] = (_Float16)1.f;

  auto compute_pair = [&](const _Float16* K0, const _Float16* K1,
                          const _Float16* V0, const _Float16* V1) {
    // --- QK^T for both tiles (independent accumulators) ---
    floatx4 scA[4] = {}, scB[4] = {};
#pragma unroll
    for (int jj = 0; jj < 4; ++jj) {
#pragma unroll
      for (int ks = 0; ks < 2; ++ks) {
        const int co = (jj * 16 + l16) * 64 + (((ks * 4 + quad) ^ rx) * 8);
        half8 akA = *(const half8*)&K0[co];
        half8 akB = *(const half8*)&K1[co];
        scA[jj] = MFMA32(akA, aq[ks], scA[jj]);
        scB[jj] = MFMA32(akB, aq[ks], scB[jj]);
      }
    }

    // --- pack to f16 (2 independent streams) ---
    half2v phA[8], phB[8];
#pragma unroll
    for (int jj = 0; jj < 4; ++jj) {
      phA[jj * 2]     = pkrtz(scA[jj][0], scA[jj][1]);
      phA[jj * 2 + 1] = pkrtz(scA[jj][2], scA[jj][3]);
      phB[jj * 2]     = pkrtz(scB[jj][0], scB[jj][1]);
      phB[jj * 2 + 1] = pkrtz(scB[jj][2], scB[jj][3]);
    }
    // --- combined max: one update per PAIR of tiles ---
    half2v mA = hmax2(hmax2(hmax2(phA[0], phA[1]), hmax2(phA[2], phA[3])),
                      hmax2(hmax2(phA[4], phA[5]), hmax2(phA[6], phA[7])));
    half2v mB = hmax2(hmax2(hmax2(phB[0], phB[1]), hmax2(phB[2], phB[3])),
                      hmax2(hmax2(phB[4], phB[5]), hmax2(phB[6], phB[7])));
    half2v mx2 = hmax2(mA, mB);
    int mi = __builtin_bit_cast(int, mx2);
    mx2 = hmax2(mx2, __builtin_bit_cast(half2v, __shfl_xor(mi, 16)));
    mi = __builtin_bit_cast(int, mx2);
    mx2 = hmax2(mx2, __builtin_bit_cast(half2v, __shfl_xor(mi, 32)));
    const float mxf = fmaxf((float)mx2[0], (float)mx2[1]);
    // defer-max: P bounded by 2^4=16, safe in f16 / f32 accum.
    const bool up = mxf > mrow + 4.0f;
    const float mn = up ? mxf : mrow;
    const float alpha = up ? exp2f(mrow - mn) : 1.0f;
    mrow = mn;

    const _Float16 mnh = (_Float16)mn;
    half2v mn2; mn2[0] = mnh; mn2[1] = mnh;
    half2v peA[8], peB[8];
#pragma unroll
    for (int i = 0; i < 8; ++i) {
      peA[i] = __builtin_elementwise_exp2(phA[i] - mn2);
      peB[i] = __builtin_elementwise_exp2(phB[i] - mn2);
    }

    if (__ballot(up)) {          // one conditional rescale per 2 tiles
      float alr[4];
#pragma unroll
      for (int r = 0; r < 4; ++r) alr[r] = __shfl(alpha, quad * 4 + r);
#pragma unroll
      for (int jb = 0; jb < 4; ++jb)
#pragma unroll
        for (int r = 0; r < 4; ++r) o16[jb][r] *= alr[r];
#pragma unroll
      for (int r = 0; r < 4; ++r) lacc[r] *= alr[r];
    }

    // --- K=32 A-frags for PV: pA[t] = [cols of block 2t | block 2t+1] ---
    half8 pA[2], pB[2];
#pragma unroll
    for (int t = 0; t < 2; ++t) {
      half4v loA = __builtin_shufflevector(peA[4 * t],     peA[4 * t + 1], 0, 1, 2, 3);
      half4v hiA = __builtin_shufflevector(peA[4 * t + 2], peA[4 * t + 3], 0, 1, 2, 3);
      pA[t] = __builtin_shufflevector(loA, hiA, 0, 1, 2, 3, 4, 5, 6, 7);
      half4v loB = __builtin_shufflevector(peB[4 * t],     peB[4 * t + 1], 0, 1, 2, 3);
      half4v hiB = __builtin_shufflevector(peB[4 * t + 2], peB[4 * t + 3], 0, 1, 2, 3);
      pB[t] = __builtin_shufflevector(loB, hiB, 0, 1, 2, 3, 4, 5, 6, 7);
    }

    // --- row-sum on the MFMA pipe: lacc[r] = sum_k P[quad*4+r][k] ---
    lacc = MFMA32(pA[0], ones8, lacc);
    lacc = MFMA32(pA[1], ones8, lacc);
    lacc = MFMA32(pB[0], ones8, lacc);
    lacc = MFMA32(pB[1], ones8, lacc);

    // --- O += P@V : 16x16x32 MFMAs, one 16B V read each ---
#pragma unroll
    for (int jb = 0; jb < 4; ++jb) {
      const int vrow = (jb * 16 + l16) * 64;
#pragma unroll
      for (int t = 0; t < 2; ++t) {
        half8 vA = *(const half8*)&V0[vrow + (((2 * quad + t) ^ rx) * 8)];
        half8 vB = *(const half8*)&V1[vrow + (((2 * quad + t) ^ rx) * 8)];
        o16[jb] = MFMA32(pA[t], vA, o16[jb]);
        o16[jb] = MFMA32(pB[t], vB, o16[jb]);
      }
    }
  };

  int cur = 0;
  for (int p = 0; p < 16; ++p) {     // 16 pairs of 64-row K/V tiles
    if (p + 1 < 16) stage(p + 1, cur ^ 1);   // DMA; flies under compute
    compute_pair(Kbuf[cur][0], Kbuf[cur][1], Vbuf[cur][0], Vbuf[cur][1]);
    __syncthreads();                         // drains vmcnt: next pair ready
    cur ^= 1;
  }

  float linv[4];
#pragma unroll
  for (int r = 0; r < 4; ++r) linv[r] = 1.0f / lacc[r];   // no shuffles needed
#pragma unroll
  for (int jb = 0; jb < 4; ++jb) {
#pragma unroll
    for (int r = 0; r < 4; ++r) {
      const int row = q0 + wave * 16 + quad * 4 + r;
      attnb[(size_t)(b * S + row) * INNER + h * HD + jb * 16 + l16] =
          (_Float16)(o16[jb][r] * linv[r]);
    }
  }
}

// ---------------------------------------------------------------------------
extern "C" void kernel_launch(void* const* d_in, const int* in_sizes, int n_in,
                              void* d_out, int out_size, void* d_ws, size_t ws_size,
                              hipStream_t stream) {
  const float* hs    = (const float*)d_in[0];
  const float* rot   = (const float*)d_in[1];
  const float* w_qkv = (const float*)d_in[2];
  const float* b_qkv = (const float*)d_in[3];
  const float* nqw   = (const float*)d_in[4];
  const float* nkw   = (const float*)d_in[5];
  const float* w_out = (const float*)d_in[6];
  const float* b_out = (const float*)d_in[7];
  const float* hks   = (const float*)d_in[8];
  const int*   octx  = (const int*)d_in[9];

  _Float16* hsb   = (_Float16*)d_ws;                 // 0-8 MiB (attnb aliases)
  _Float16* attnb = hsb;
  _Float16* wqkvT = hsb   + (size_t)NTOK * DIM;      // 8-14 MiB
  _Float16* woutT = wqkvT + (size_t)QKVN * DIM;      // 14-16 MiB
  _Float16* qkvh  = woutT + (size_t)DIM * INNER;     // 16-40 MiB
  _Float16* q_h   = qkvh  + (size_t)NTOK * QKVN;     // 40-48 MiB
  _Float16* k_h   = q_h   + (size_t)B * NH * S * HD; // 48-56 MiB
  _Float16* vT    = k_h   + (size_t)B * NH * S * HD; // 56-64 MiB

  prep_all<<<3072, 256, 0, stream>>>(hs, w_qkv, w_out, hsb, wqkvT, woutT);

  gemm_bt<true, _Float16><<<dim3(QKVN / 128, NTOK / 128), 256, 0, stream>>>(
      hsb, wqkvT, b_qkv, qkvh, QKVN, DIM);

  post_all<<<5120, 256, 0, stream>>>(qkvh, rot, nqw, nkw, hks, octx, q_h, k_h, vT);

  attn_mfma<<<dim3(B * NH, S / 128), 512, 0, stream>>>(q_h, k_h, vT, attnb);

  gemm_bt<false, float><<<dim3(DIM / 128, NTOK / 128), 256, 0, stream>>>(
      attnb, woutT, b_out, (float*)d_out, DIM, INNER);
}